// Round 8
// baseline (1947.275 us; speedup 1.0000x reference)
//
#include <hip/hip_runtime.h>
#include <stdint.h>

#define DEV static __device__ __forceinline__

typedef __attribute__((ext_vector_type(4))) float f32x4;
typedef __attribute__((ext_vector_type(8))) short bf16x8;
typedef __attribute__((ext_vector_type(4))) short s16x4;

// dims
static constexpr int L_ = 6, T_ = 128, NE = 32, D_ = 1024, H_ = 16, DH_ = 64, M_ = 128, DI_ = 4096;
static constexpr int KLEN = M_ + T_;   // 256
static constexpr int TN = T_ * NE;     // 4096
static constexpr int NB = NE * H_;     // 512 attention batches

DEV unsigned short f2bf(float f) {
  unsigned u = __builtin_bit_cast(unsigned, f);
  u += 0x7FFFu + ((u >> 16) & 1u);
  return (unsigned short)(u >> 16);
}
DEV float bf2f(unsigned short h) {
  unsigned u = ((unsigned)h) << 16;
  return __builtin_bit_cast(float, u);
}

DEV void gload16(const unsigned short* g, unsigned short* lds) {
  __builtin_amdgcn_global_load_lds(
      (const __attribute__((address_space(1))) unsigned int*)g,
      (__attribute__((address_space(3))) unsigned int*)lds, 16, 0, 0);
}

#define WAITV0 asm volatile("s_waitcnt vmcnt(0)" ::: "memory")

// ---------------------------------------------------------------------------
// 128x128 tile core, BK=64, 4 waves (2x2). T2 XOR-swizzle, 2-phase.
// ---------------------------------------------------------------------------
DEV void stage128(const unsigned short* __restrict__ Ab, int lda,
                  const unsigned short* __restrict__ Bb, int ldb,
                  unsigned short* lA, unsigned short* lB,
                  int m0, int n0, int k0, int w, int l)
{
#pragma unroll
  for (int i = 0; i < 4; ++i) {
    const int obb = i * 4096 + w * 1024;
    const int ob  = obb + (l << 4);
    const int row = ob >> 7;
    const int col = (((ob >> 4) & 7) ^ (row & 7)) << 3;
    gload16(Ab + (size_t)(m0 + row) * lda + k0 + col, lA + (obb >> 1));
    gload16(Bb + (size_t)(n0 + row) * ldb + k0 + col, lB + (obb >> 1));
  }
}

DEV void compute128(const unsigned short* lA, const unsigned short* lB,
                    int w, int l, f32x4 acc[4][4])
{
  const int wr = (w >> 1) * 64, wc = (w & 1) * 64;
  const int lan = l & 15, lgr = l >> 4;
#pragma unroll
  for (int ks = 0; ks < 2; ++ks) {
    bf16x8 av[4], bv[4];
#pragma unroll
    for (int m = 0; m < 4; ++m) {
      const int row = wr + m * 16 + lan;
      const int byte = ((row << 7) + (ks << 6) + (lgr << 4)) ^ ((row & 7) << 4);
      av[m] = *(const bf16x8*)((const char*)lA + byte);
    }
#pragma unroll
    for (int n = 0; n < 4; ++n) {
      const int row = wc + n * 16 + lan;
      const int byte = ((row << 7) + (ks << 6) + (lgr << 4)) ^ ((row & 7) << 4);
      bv[n] = *(const bf16x8*)((const char*)lB + byte);
    }
#pragma unroll
    for (int m = 0; m < 4; ++m)
#pragma unroll
      for (int n = 0; n < 4; ++n)
        acc[m][n] = __builtin_amdgcn_mfma_f32_16x16x32_bf16(av[m], bv[n], acc[m][n], 0, 0, 0);
  }
}

DEV void gemm128_2ph(const unsigned short* __restrict__ Ab, int lda,
                     const unsigned short* __restrict__ Bb, int ldb,
                     unsigned short (*shA)[8192], unsigned short (*shB)[8192],
                     int m0, int n0, int nK, int w, int l, f32x4 acc[4][4])
{
  stage128(Ab, lda, Bb, ldb, shA[0], shB[0], m0, n0, 0, w, l);
  WAITV0;
  __syncthreads();
  int cur = 0;
  for (int kt = 0; kt < nK; ++kt) {
    if (kt + 1 < nK)
      stage128(Ab, lda, Bb, ldb, shA[cur ^ 1], shB[cur ^ 1], m0, n0, (kt + 1) * 64, w, l);
    compute128(shA[cur], shB[cur], w, l, acc);
    WAITV0;
    __syncthreads();
    cur ^= 1;
  }
}

// ---------------------------------------------------------------------------
// 256x256 tile core, BK=64, 8 waves (2M x 4N), SAME 2-phase schedule and
// SAME &7 swizzle as the 128^2 core (R4's failure was BK=32 + depth-3 +
// a 4-chunk swizzle — not tile size). LDS 128 KB double-buffered, 1 blk/CU.
// Per K-step: 64 MFMA per 24 ds_read per wave (vs 32:16) and 0.5 B/FLOP
// staged (vs 1.0) -> the vmcnt(0) drain amortizes 2x better.
// ---------------------------------------------------------------------------
DEV void stage256(const unsigned short* __restrict__ Ab, int lda,
                  const unsigned short* __restrict__ Bb, int ldb,
                  unsigned short* lA, unsigned short* lB,
                  int m0, int n0, int k0, int t)
{
#pragma unroll
  for (int i = 0; i < 4; ++i) {
    const int obb = i * 8192 + (t >> 6) * 1024;
    const int ob  = obb + ((t & 63) << 4);
    const int row = ob >> 7;
    const int col = (((ob >> 4) & 7) ^ (row & 7)) << 3;
    gload16(Ab + (size_t)(m0 + row) * lda + k0 + col, lA + (obb >> 1));
    gload16(Bb + (size_t)(n0 + row) * ldb + k0 + col, lB + (obb >> 1));
  }
}

DEV void compute256(const unsigned short* lA, const unsigned short* lB,
                    int w, int l, f32x4 acc[8][4])
{
  const int wm = w >> 2, wn = w & 3;
  const int lan = l & 15, lgr = l >> 4;
#pragma unroll
  for (int ks = 0; ks < 2; ++ks) {
    bf16x8 av[8], bv[4];
#pragma unroll
    for (int m = 0; m < 8; ++m) {
      const int row = wm * 128 + m * 16 + lan;
      const int byte = ((row << 7) + (ks << 6) + (lgr << 4)) ^ ((row & 7) << 4);
      av[m] = *(const bf16x8*)((const char*)lA + byte);
    }
#pragma unroll
    for (int n = 0; n < 4; ++n) {
      const int row = wn * 64 + n * 16 + lan;
      const int byte = ((row << 7) + (ks << 6) + (lgr << 4)) ^ ((row & 7) << 4);
      bv[n] = *(const bf16x8*)((const char*)lB + byte);
    }
#pragma unroll
    for (int m = 0; m < 8; ++m)
#pragma unroll
      for (int n = 0; n < 4; ++n)
        acc[m][n] = __builtin_amdgcn_mfma_f32_16x16x32_bf16(av[m], bv[n], acc[m][n], 0, 0, 0);
  }
}

DEV void gemm256_2ph(const unsigned short* __restrict__ Ab, int lda,
                     const unsigned short* __restrict__ Bb, int ldb,
                     unsigned short (*shA)[16384], unsigned short (*shB)[16384],
                     int m0, int n0, int nK, int t, f32x4 acc[8][4])
{
  const int w = t >> 6, l = t & 63;
  stage256(Ab, lda, Bb, ldb, shA[0], shB[0], m0, n0, 0, t);
  WAITV0;
  __syncthreads();
  int cur = 0;
  for (int kt = 0; kt < nK; ++kt) {
    if (kt + 1 < nK)
      stage256(Ab, lda, Bb, ldb, shA[cur ^ 1], shB[cur ^ 1], m0, n0, (kt + 1) * 64, t);
    compute256(shA[cur], shB[cur], w, l, acc);
    WAITV0;
    __syncthreads();
    cur ^= 1;
  }
}

// 256^2 GEMM, split-K via blockIdx.z. EPI: 0=f32, 2=bf16(bias+relu)
template <int EPI>
__global__ __launch_bounds__(512) void gemm256_bt(
    const unsigned short* __restrict__ A, int lda, int sAh,
    const unsigned short* __restrict__ B, int ldb, int sBh,
    void* __restrict__ Cv, int ldc, size_t sC,
    const float* __restrict__ bias, int nK)
{
  __shared__ unsigned short shA[2][16384];
  __shared__ unsigned short shB[2][16384];
  const int z = blockIdx.z;
  const int m0 = blockIdx.y * 256, n0 = blockIdx.x * 256;
  const int t = threadIdx.x;

  f32x4 acc[8][4];
#pragma unroll
  for (int m = 0; m < 8; ++m)
#pragma unroll
    for (int n = 0; n < 4; ++n) acc[m][n] = (f32x4){0.f, 0.f, 0.f, 0.f};

  gemm256_2ph(A + (size_t)z * sAh, lda, B + (size_t)z * sBh, ldb,
              shA, shB, m0, n0, nK, t, acc);

  const int w = t >> 6, l = t & 63;
  const int wm = w >> 2, wn = w & 3, lan = l & 15, lgr = l >> 4;
  const size_t zc = (size_t)z * sC;
#pragma unroll
  for (int m = 0; m < 8; ++m) {
    const int row = m0 + wm * 128 + m * 16 + lgr * 4;
#pragma unroll
    for (int n = 0; n < 4; ++n) {
      const int col = n0 + wn * 64 + n * 16 + lan;
      const float bcol = (EPI >= 2) ? bias[col] : 0.f;
#pragma unroll
      for (int e = 0; e < 4; ++e) {
        float v = acc[m][n][e];
        const size_t idx = zc + (size_t)(row + e) * ldc + col;
        if (EPI == 0) {
          ((float*)Cv)[idx] = v;
        } else {
          v += bcol; v = v > 0.f ? v : 0.f;
          ((unsigned short*)Cv)[idx] = f2bf(v);
        }
      }
    }
  }
}

// ---------------------------------------------------------------------------
// Fused projection GEMM: [cat(8192 rows) ; R(256 rows)] @ [Wk|Wv|Wq|Wr]^T
// (128^2 tiles — 1296 blocks pack the CUs better than a 332-block 256^2 grid)
// ---------------------------------------------------------------------------
__global__ __launch_bounds__(256) void gemm_proj(
    const unsigned short* __restrict__ catA, const unsigned short* __restrict__ wt,
    unsigned short* __restrict__ kb, unsigned short* __restrict__ vb,
    unsigned short* __restrict__ qw, unsigned short* __restrict__ qr,
    unsigned short* __restrict__ rb,
    const float* __restrict__ rwb, const float* __restrict__ rrb)
{
  __shared__ unsigned short shA[2][8192];
  __shared__ unsigned short shB[2][8192];

  const int id = blockIdx.x;
  int by, bx;
  if (id < 1024)      { by = id >> 4;               bx = id & 15; }
  else if (id < 1280) { const int u = id - 1024; by = 32 + (u >> 3); bx = 16 + (u & 7); }
  else                { const int u = id - 1280; by = 64 + (u >> 3); bx = 24 + (u & 7); }
  const int m0 = by * 128, n0 = bx * 128;

  const int t = threadIdx.x;
  const int w = t >> 6, l = t & 63;
  const int wr = (w >> 1) * 64, wc = (w & 1) * 64;
  const int lan = l & 15, lgr = l >> 4;

  f32x4 acc[4][4];
#pragma unroll
  for (int m = 0; m < 4; ++m)
#pragma unroll
    for (int n = 0; n < 4; ++n) acc[m][n] = (f32x4){0.f, 0.f, 0.f, 0.f};

  gemm128_2ph(catA, 1024, wt, 1024, shA, shB, m0, n0, 16, w, l, acc);

#pragma unroll
  for (int m = 0; m < 4; ++m) {
    const int row = m0 + wr + m * 16 + lgr * 4;
#pragma unroll
    for (int n = 0; n < 4; ++n) {
      const int col = n0 + wc + n * 16 + lan;
#pragma unroll
      for (int e = 0; e < 4; ++e) {
        const float v = acc[m][n][e];
        const int r = row + e;
        if (col < 1024) {
          kb[(size_t)r * 1024 + col] = f2bf(v);
        } else if (col < 2048) {
          vb[(size_t)r * 1024 + col - 1024] = f2bf(v);
        } else if (col < 3072) {
          const int c = col - 2048;
          const size_t o = (size_t)(r - 4096) * 1024 + c;
          qw[o] = f2bf(v + rwb[c]);
          qr[o] = f2bf(v + rrb[c]);
        } else {
          const int c = col - 3072;
          rb[(size_t)(r - 8192) * 1024 + c] = f2bf(v);
        }
      }
    }
  }
}

// ---------------------------------------------------------------------------
// Fully fused attention: AC + shifted-BD + masked softmax + PV.
// One block per z=(nn,hh), 4 waves, zero barriers (wave-local LDS).
// ---------------------------------------------------------------------------
__global__ __launch_bounds__(256) void attn_kernel(
    const unsigned short* __restrict__ qw, const unsigned short* __restrict__ qr,
    const unsigned short* __restrict__ kbf, const unsigned short* __restrict__ rbf,
    const int* __restrict__ ep, const unsigned short* __restrict__ V,
    unsigned short* __restrict__ O)
{
  __shared__ unsigned short sS[4][32 * 256];   // 64 KB

  const int z = blockIdx.x;
  const int nn = z >> 4, hh = z & 15;
  const int t = threadIdx.x, w = t >> 6, l = t & 63;
  const int lan = l & 15, lgr = l >> 4;
  const int i0 = w * 32;
  unsigned short* S = sS[w];

  // ---- AC = (q + r_w_bias) . K^T  -> S ----
  bf16x8 av[2][2];
#pragma unroll
  for (int m = 0; m < 2; ++m)
#pragma unroll
    for (int kk = 0; kk < 2; ++kk) {
      const int i = i0 + m * 16 + lan;
      av[m][kk] = *(const bf16x8*)&qw[(size_t)(i * NE + nn) * 1024 + hh * 64 + kk * 32 + lgr * 8];
    }
#pragma unroll
  for (int n = 0; n < 16; ++n) {
    bf16x8 bv[2];
#pragma unroll
    for (int kk = 0; kk < 2; ++kk) {
      const int j = n * 16 + lan;
      bv[kk] = *(const bf16x8*)&kbf[(size_t)(j * NE + nn) * 1024 + hh * 64 + kk * 32 + lgr * 8];
    }
#pragma unroll
    for (int m = 0; m < 2; ++m) {
      f32x4 a4 = (f32x4){0.f, 0.f, 0.f, 0.f};
#pragma unroll
      for (int kk = 0; kk < 2; ++kk)
        a4 = __builtin_amdgcn_mfma_f32_16x16x32_bf16(av[m][kk], bv[kk], a4, 0, 0, 0);
#pragma unroll
      for (int e = 0; e < 4; ++e) {
        const int r = m * 16 + lgr * 4 + e;
        const int j = n * 16 + lan;
        const int swz = ((r >> 2) & 3) * 16;
        S[r * 256 + (j ^ swz)] = f2bf(a4[e]);
      }
    }
  }

  // ---- BD = (q + r_r_bias) . R^T, scatter-add with shift j = j' + i - 127 ----
  bf16x8 bq[2][2];
#pragma unroll
  for (int m = 0; m < 2; ++m)
#pragma unroll
    for (int kk = 0; kk < 2; ++kk) {
      const int i = i0 + m * 16 + lan;
      bq[m][kk] = *(const bf16x8*)&qr[(size_t)(i * NE + nn) * 1024 + hh * 64 + kk * 32 + lgr * 8];
    }
#pragma unroll
  for (int n = 0; n < 16; ++n) {
    bf16x8 bv[2];
#pragma unroll
    for (int kk = 0; kk < 2; ++kk) {
      const int jp = n * 16 + lan;
      bv[kk] = *(const bf16x8*)&rbf[(size_t)jp * 1024 + hh * 64 + kk * 32 + lgr * 8];
    }
#pragma unroll
    for (int m = 0; m < 2; ++m) {
      f32x4 a4 = (f32x4){0.f, 0.f, 0.f, 0.f};
#pragma unroll
      for (int kk = 0; kk < 2; ++kk)
        a4 = __builtin_amdgcn_mfma_f32_16x16x32_bf16(bq[m][kk], bv[kk], a4, 0, 0, 0);
#pragma unroll
      for (int e = 0; e < 4; ++e) {
        const int r = m * 16 + lgr * 4 + e;
        const int i = i0 + r;
        const int jp = n * 16 + lan;
        const int j = jp + i - 127;
        if (j >= 0 && j < 256) {
          const int swz = ((r >> 2) & 3) * 16;
          const int idx = r * 256 + (j ^ swz);
          S[idx] = f2bf(bf2f(S[idx]) + a4[e]);
        }
      }
    }
  }

  // ---- masked softmax, in place ----
  const int j0 = l * 4;
  for (int rr = 0; rr < 32; ++rr) {
    const int i = i0 + rr;
    const int epi = ep[i * NE + nn];
    const int swz = ((rr >> 2) & 3) * 16;
    s16x4 s4 = *(const s16x4*)&S[rr * 256 + (j0 ^ swz)];
    float sc[4];
#pragma unroll
    for (int q = 0; q < 4; ++q) {
      const int j = j0 + q;
      bool allow;
      if (j < M_) {
        allow = (epi == 0);
      } else {
        const int jp = j - M_;
        allow = (jp <= i) && (ep[jp * NE + nn] == epi);
      }
      sc[q] = allow ? bf2f((unsigned short)s4[q]) * 0.125f : -1e9f;
    }
    float mx = fmaxf(fmaxf(sc[0], sc[1]), fmaxf(sc[2], sc[3]));
#pragma unroll
    for (int o = 32; o; o >>= 1) mx = fmaxf(mx, __shfl_xor(mx, o));
    float p[4], sum = 0.f;
#pragma unroll
    for (int q = 0; q < 4; ++q) { p[q] = __expf(sc[q] - mx); sum += p[q]; }
#pragma unroll
    for (int o = 32; o; o >>= 1) sum += __shfl_xor(sum, o);
    const float inv = 1.f / sum;
    s16x4 o4;
#pragma unroll
    for (int q = 0; q < 4; ++q) o4[q] = (short)f2bf(p[q] * inv);
    *(s16x4*)&S[rr * 256 + (j0 ^ swz)] = o4;
  }

  // ---- PV ----
  const unsigned short* Vz = V + hh * DH_;
  f32x4 acc[2][4];
#pragma unroll
  for (int m = 0; m < 2; ++m)
#pragma unroll
    for (int n = 0; n < 4; ++n) acc[m][n] = (f32x4){0.f, 0.f, 0.f, 0.f};

  for (int ks = 0; ks < 8; ++ks) {
    const int kb = ks * 32 + lgr * 8;
    bf16x8 bv2[4];
#pragma unroll
    for (int n = 0; n < 4; ++n) {
      const int d = n * 16 + lan;
      bf16x8 tmp;
#pragma unroll
      for (int jj = 0; jj < 8; ++jj)
        tmp[jj] = (short)Vz[(size_t)((kb + jj) * NE + nn) * 1024 + d];
      bv2[n] = tmp;
    }
    bf16x8 pa[2];
#pragma unroll
    for (int m = 0; m < 2; ++m) {
      const int r = m * 16 + lan;
      const int swz = ((r >> 2) & 3) * 16;
      pa[m] = *(const bf16x8*)&S[r * 256 + (kb ^ swz)];
    }
#pragma unroll
    for (int m = 0; m < 2; ++m)
#pragma unroll
      for (int n = 0; n < 4; ++n)
        acc[m][n] = __builtin_amdgcn_mfma_f32_16x16x32_bf16(pa[m], bv2[n], acc[m][n], 0, 0, 0);
  }
#pragma unroll
  for (int m = 0; m < 2; ++m)
#pragma unroll
    for (int n = 0; n < 4; ++n)
#pragma unroll
      for (int e = 0; e < 4; ++e) {
        const int i = i0 + m * 16 + lgr * 4 + e;
        const int d = n * 16 + lan;
        O[(size_t)(i * NE + nn) * 1024 + hh * DH_ + d] = f2bf(acc[m][n][e]);
      }
}

// ---------------------------------------------------------------------------
__global__ __launch_bounds__(256) void transpose_kernel(
    const float* __restrict__ W, unsigned short* __restrict__ WT, int Kd, int Nd)
{
  __shared__ float tile[32][33];
  const int tx = threadIdx.x & 31, ty = threadIdx.x >> 5;
  const int nIn = blockIdx.x * 32 + tx;
  const int kBase = blockIdx.y * 32;
#pragma unroll
  for (int r = 0; r < 32; r += 8)
    tile[ty + r][tx] = W[(size_t)(kBase + ty + r) * Nd + nIn];
  __syncthreads();
#pragma unroll
  for (int r = 0; r < 32; r += 8)
    WT[(size_t)(blockIdx.x * 32 + ty + r) * Kd + kBase + tx] = f2bf(tile[tx][ty + r]);
}

__global__ __launch_bounds__(256) void transpose5_kernel(
    const float* __restrict__ Wk, const float* __restrict__ Wv,
    const float* __restrict__ Wq, const float* __restrict__ Wr,
    const float* __restrict__ Wo,
    unsigned short* __restrict__ wtAll, unsigned short* __restrict__ wto)
{
  __shared__ float tile[32][33];
  const int zz = blockIdx.z;
  const float* W = (zz == 0) ? Wk : (zz == 1) ? Wv : (zz == 2) ? Wq : (zz == 3) ? Wr : Wo;
  unsigned short* WT = (zz == 4) ? wto : (wtAll + (size_t)zz * 1024 * 1024);
  const int tx = threadIdx.x & 31, ty = threadIdx.x >> 5;
  const int nIn = blockIdx.x * 32 + tx;
  const int kBase = blockIdx.y * 32;
#pragma unroll
  for (int r = 0; r < 32; r += 8)
    tile[ty + r][tx] = W[(size_t)(kBase + ty + r) * 1024 + nIn];
  __syncthreads();
#pragma unroll
  for (int r = 0; r < 32; r += 8)
    WT[(size_t)(blockIdx.x * 32 + ty + r) * 1024 + kBase + tx] = f2bf(tile[tx][ty + r]);
}

__global__ __launch_bounds__(256) void catmem_kernel(
    const float* __restrict__ mems_l, const float* __restrict__ masks,
    unsigned short* __restrict__ cat)
{
  const int idx = blockIdx.x * 256 + threadIdx.x;
  const int d = idx & 1023;
  const int r = idx >> 10;
  const int nn = r & 31, j = r >> 5;
  const float mk0 = masks[nn];
  cat[idx] = f2bf(mems_l[(size_t)(nn * M_ + j) * 1024 + d] * mk0);
}

__global__ __launch_bounds__(256) void hprep_kernel(
    const float* __restrict__ x, const float* __restrict__ ctx,
    float* __restrict__ h, unsigned short* __restrict__ catUp)
{
  const int idx = blockIdx.x * 256 + threadIdx.x;
  const float v = x[idx] + ctx[idx];
  h[idx] = v;
  catUp[idx] = f2bf(v);
}

__global__ __launch_bounds__(256) void rpos_kernel(unsigned short* __restrict__ R)
{
  const int idx = blockIdx.x * 256 + threadIdx.x;
  const int d = idx & 1023, j = idx >> 10;
  const float pos = (float)(KLEN - 1 - j);
  const int f = d & 511;
  const float inv_freq = __expf(-((float)(2 * f) * (1.f / 1024.f)) * 9.210340371976184f);
  const float ang = pos * inv_freq;
  const float v = (d < 512) ? sinf(ang) : cosf(ang);
  R[idx] = f2bf(v);
}

__global__ void ep_kernel(const float* __restrict__ masks, int* __restrict__ ep)
{
  const int nn = threadIdx.x;
  if (nn < NE) {
    int c = 0;
    for (int i = 0; i < T_; ++i) {
      c += (masks[i * NE + nn] == 0.f) ? 1 : 0;
      ep[i * NE + nn] = c;
    }
  }
}

// y = LN(a + sum_{i<NP} parts[i] + bias) * g + b
template <int NP>
__global__ __launch_bounds__(256) void ln_kernel(
    const float* __restrict__ a, const float* __restrict__ parts, size_t pstride,
    const float* __restrict__ bias,
    const float* __restrict__ g, const float* __restrict__ bb,
    float* __restrict__ outf, unsigned short* __restrict__ outbf)
{
  const int row = blockIdx.x;
  const int t = threadIdx.x, w = t >> 6, l = t & 63;
  const int c = t * 4;
  const size_t base = (size_t)row * 1024;
  f32x4 v = *(const f32x4*)&a[base + c];
#pragma unroll
  for (int i = 0; i < NP; ++i)
    v = v + *(const f32x4*)&parts[i * pstride + base + c];
  if (bias) v = v + *(const f32x4*)&bias[c];
  float s = v[0] + v[1] + v[2] + v[3];
#pragma unroll
  for (int o = 32; o; o >>= 1) s += __shfl_xor(s, o);
  __shared__ float red[8];
  if (l == 0) red[w] = s;
  __syncthreads();
  s = red[0] + red[1] + red[2] + red[3];
  const float mu = s * (1.f / 1024.f);
  f32x4 dv = v - mu;
  float s2 = dv[0]*dv[0] + dv[1]*dv[1] + dv[2]*dv[2] + dv[3]*dv[3];
#pragma unroll
  for (int o = 32; o; o >>= 1) s2 += __shfl_xor(s2, o);
  if (l == 0) red[4 + w] = s2;
  __syncthreads();
  s2 = red[4] + red[5] + red[6] + red[7];
  const float inv = rsqrtf(s2 * (1.f / 1024.f) + 1e-5f);
  f32x4 y;
#pragma unroll
  for (int q = 0; q < 4; ++q) y[q] = dv[q] * inv * g[c + q] + bb[c + q];
  *(f32x4*)&outf[base + c] = y;
  if (outbf) {
    s16x4 o4;
#pragma unroll
    for (int q = 0; q < 4; ++q) o4[q] = (short)f2bf(y[q]);
    *(s16x4*)&outbf[base + c] = o4;
  }
}

// ---------------------------------------------------------------------------
extern "C" void kernel_launch(void* const* d_in, const int* in_sizes, int n_in,
                              void* d_out, int out_size, void* d_ws, size_t ws_size,
                              hipStream_t stream)
{
  (void)in_sizes; (void)n_in; (void)out_size; (void)ws_size;
  const float* x    = (const float*)d_in[0];
  const float* ctx  = (const float*)d_in[1];
  const float* mems = (const float*)d_in[2];
  const float* masks= (const float*)d_in[3];
  const float* Wq   = (const float*)d_in[4];
  const float* Wk   = (const float*)d_in[5];
  const float* Wv   = (const float*)d_in[6];
  const float* Wr   = (const float*)d_in[7];
  const float* Wo   = (const float*)d_in[8];
  const float* W1   = (const float*)d_in[9];
  const float* b1   = (const float*)d_in[10];
  const float* W2   = (const float*)d_in[11];
  const float* b2   = (const float*)d_in[12];
  const float* ln1g = (const float*)d_in[13];
  const float* ln1b = (const float*)d_in[14];
  const float* ln2g = (const float*)d_in[15];
  const float* ln2b = (const float*)d_in[16];
  const float* rwb  = (const float*)d_in[17];
  const float* rrb  = (const float*)d_in[18];

  char* ws = (char*)d_ws;
  size_t off = 0;
  auto alloc = [&](size_t bytes) {
    char* p = ws + off;
    off += (bytes + 255) & ~(size_t)255;
    return p;
  };
  unsigned short* wtAll = (unsigned short*)alloc(4096u * 1024 * 2);  // [Wk|Wv|Wq|Wr]^T
  unsigned short* wto = (unsigned short*)alloc(1024u * 1024 * 2);
  unsigned short* wt1 = (unsigned short*)alloc(4096u * 1024 * 2);
  unsigned short* wt2 = (unsigned short*)alloc(4096u * 1024 * 2);
  unsigned short* cat = (unsigned short*)alloc((size_t)(KLEN * NE + 256) * 1024 * 2);
  unsigned short* rbf = (unsigned short*)alloc((size_t)KLEN * 1024 * 2);
  int*            epb = (int*)alloc((size_t)T_ * NE * 4);
  float*          h   = (float*)alloc((size_t)TN * 1024 * 4);
  float*          h1  = (float*)alloc((size_t)TN * 1024 * 4);
  unsigned short* qw  = (unsigned short*)alloc((size_t)TN * 1024 * 2);   // alias: h1_bf
  unsigned short* qr  = (unsigned short*)alloc((size_t)TN * 1024 * 2);
  unsigned short* kbf = (unsigned short*)alloc((size_t)KLEN * NE * 1024 * 2);
  unsigned short* vbf = (unsigned short*)alloc((size_t)KLEN * NE * 1024 * 2);
  unsigned short* ACb = (unsigned short*)alloc((size_t)NB * T_ * KLEN * 2); // alias: f1
  unsigned short* BDb = (unsigned short*)alloc((size_t)NB * T_ * KLEN * 2); // part 0,1
  float*          pex = (float*)alloc((size_t)2 * TN * 1024 * 4);          // part 2,3
  unsigned short* obf = (unsigned short*)alloc((size_t)TN * 1024 * 2);

  (void)pex;  // contiguous with BDb: part spans both
  unsigned short* catUp = cat + (size_t)M_ * NE * 1024;     // h rows (4096..8191)
  unsigned short* catR  = cat + (size_t)KLEN * NE * 1024;   // R rows (8192..8447)
  unsigned short* f1 = ACb;                 // W1 out
  float* part = (float*)BDb;                // 4 split-K partials (BDb + pex)
  unsigned short* h1bf = qw;                // qw dead after attn

  rpos_kernel<<<KLEN * 1024 / 256, 256, 0, stream>>>(catR);
  ep_kernel<<<1, 64, 0, stream>>>(masks, epb);
  hprep_kernel<<<TN * 1024 / 256, 256, 0, stream>>>(x, ctx, h, catUp);

  for (int l = 0; l < L_; ++l) {
    const size_t wOff = (size_t)l * 1024 * 1024;
    const size_t wOffBig = (size_t)l * 1024 * 4096;
    transpose5_kernel<<<dim3(32, 32, 5), 256, 0, stream>>>(
        Wk + wOff, Wv + wOff, Wq + wOff, Wr + wOff, Wo + wOff, wtAll, wto);
    transpose_kernel<<<dim3(128, 32), 256, 0, stream>>>(W1 + wOffBig, wt1, 1024, 4096);
    transpose_kernel<<<dim3(32, 128), 256, 0, stream>>>(W2 + wOffBig, wt2, 4096, 1024);
    catmem_kernel<<<M_ * NE * 1024 / 256, 256, 0, stream>>>(
        mems + (size_t)l * NE * M_ * 1024, masks, cat);

    // fused k|v|q|r projection (1296 blocks, 128^2 tiles, 2-phase)
    gemm_proj<<<1296, 256, 0, stream>>>(cat, wtAll, kbf, vbf, qw, qr, rbf, rwb, rrb);

    // fully fused attention (scores + rel_shift + masked softmax + PV)
    attn_kernel<<<NB, 256, 0, stream>>>(qw, qr, kbf, rbf, epb, vbf, obf);

    // output projection: 256^2, split-K=4 (4x16x4 = 256 blocks, 1 round)
    gemm256_bt<0><<<dim3(4, 16, 4), 512, 0, stream>>>(
        obf, 1024, 256, wto, 1024, 256,
        part, 1024, (size_t)TN * 1024, nullptr, 4);
    ln_kernel<4><<<TN, 256, 0, stream>>>(h, part, (size_t)TN * 1024, nullptr,
                                         ln1g + l * 1024, ln1b + l * 1024, h1, h1bf);

    // FFN: W1 on 256^2 (16x16 = 256 blocks, 1 round), bias+relu fused
    gemm256_bt<2><<<dim3(16, 16, 1), 512, 0, stream>>>(
        h1bf, 1024, 0, wt1, 1024, 0,
        f1, 4096, (size_t)0, b1 + l * 4096, 16);
    // W2: 256^2, split-K=4 (4x16x4 = 256 blocks, 1 round)
    gemm256_bt<0><<<dim3(4, 16, 4), 512, 0, stream>>>(
        f1, 4096, 1024, wt2, 4096, 1024,
        part, 1024, (size_t)TN * 1024, nullptr, 16);
    ln_kernel<4><<<TN, 256, 0, stream>>>(h1, part, (size_t)TN * 1024, b2 + l * 1024,
                                         ln2g + l * 1024, ln2b + l * 1024,
                                         (l == L_ - 1) ? (float*)d_out : h, catUp);
  }
}

// Round 9
// 1935.498 us; speedup vs baseline: 1.0061x; 1.0061x over previous
//
#include <hip/hip_runtime.h>
#include <stdint.h>

#define DEV static __device__ __forceinline__

typedef __attribute__((ext_vector_type(4))) float f32x4;
typedef __attribute__((ext_vector_type(8))) short bf16x8;
typedef __attribute__((ext_vector_type(4))) short s16x4;

// dims
static constexpr int L_ = 6, T_ = 128, NE = 32, D_ = 1024, H_ = 16, DH_ = 64, M_ = 128, DI_ = 4096;
static constexpr int KLEN = M_ + T_;   // 256
static constexpr int TN = T_ * NE;     // 4096
static constexpr int NB = NE * H_;     // 512 attention batches

DEV unsigned short f2bf(float f) {
  unsigned u = __builtin_bit_cast(unsigned, f);
  u += 0x7FFFu + ((u >> 16) & 1u);
  return (unsigned short)(u >> 16);
}
DEV float bf2f(unsigned short h) {
  unsigned u = ((unsigned)h) << 16;
  return __builtin_bit_cast(float, u);
}

DEV void gload16(const unsigned short* g, unsigned short* lds) {
  __builtin_amdgcn_global_load_lds(
      (const __attribute__((address_space(1))) unsigned int*)g,
      (__attribute__((address_space(3))) unsigned int*)lds, 16, 0, 0);
}

#define WAITV0 asm volatile("s_waitcnt vmcnt(0)" ::: "memory")

// ---------------------------------------------------------------------------
// 128x128 tile core, BK=64, 4 waves (2x2). T2 XOR-swizzle, 2-phase.
// ---------------------------------------------------------------------------
DEV void stage128(const unsigned short* __restrict__ Ab, int lda,
                  const unsigned short* __restrict__ Bb, int ldb,
                  unsigned short* lA, unsigned short* lB,
                  int m0, int n0, int k0, int w, int l)
{
#pragma unroll
  for (int i = 0; i < 4; ++i) {
    const int obb = i * 4096 + w * 1024;
    const int ob  = obb + (l << 4);
    const int row = ob >> 7;
    const int col = (((ob >> 4) & 7) ^ (row & 7)) << 3;
    gload16(Ab + (size_t)(m0 + row) * lda + k0 + col, lA + (obb >> 1));
    gload16(Bb + (size_t)(n0 + row) * ldb + k0 + col, lB + (obb >> 1));
  }
}

DEV void compute128(const unsigned short* lA, const unsigned short* lB,
                    int w, int l, f32x4 acc[4][4])
{
  const int wr = (w >> 1) * 64, wc = (w & 1) * 64;
  const int lan = l & 15, lgr = l >> 4;
#pragma unroll
  for (int ks = 0; ks < 2; ++ks) {
    bf16x8 av[4], bv[4];
#pragma unroll
    for (int m = 0; m < 4; ++m) {
      const int row = wr + m * 16 + lan;
      const int byte = ((row << 7) + (ks << 6) + (lgr << 4)) ^ ((row & 7) << 4);
      av[m] = *(const bf16x8*)((const char*)lA + byte);
    }
#pragma unroll
    for (int n = 0; n < 4; ++n) {
      const int row = wc + n * 16 + lan;
      const int byte = ((row << 7) + (ks << 6) + (lgr << 4)) ^ ((row & 7) << 4);
      bv[n] = *(const bf16x8*)((const char*)lB + byte);
    }
#pragma unroll
    for (int m = 0; m < 4; ++m)
#pragma unroll
      for (int n = 0; n < 4; ++n)
        acc[m][n] = __builtin_amdgcn_mfma_f32_16x16x32_bf16(av[m], bv[n], acc[m][n], 0, 0, 0);
  }
}

DEV void gemm128_2ph(const unsigned short* __restrict__ Ab, int lda,
                     const unsigned short* __restrict__ Bb, int ldb,
                     unsigned short (*shA)[8192], unsigned short (*shB)[8192],
                     int m0, int n0, int nK, int w, int l, f32x4 acc[4][4])
{
  stage128(Ab, lda, Bb, ldb, shA[0], shB[0], m0, n0, 0, w, l);
  WAITV0;
  __syncthreads();
  int cur = 0;
  for (int kt = 0; kt < nK; ++kt) {
    if (kt + 1 < nK)
      stage128(Ab, lda, Bb, ldb, shA[cur ^ 1], shB[cur ^ 1], m0, n0, (kt + 1) * 64, w, l);
    compute128(shA[cur], shB[cur], w, l, acc);
    WAITV0;
    __syncthreads();
    cur ^= 1;
  }
}

// ---------------------------------------------------------------------------
// Generic batched GEMM: C[M,N] = A[M,K] @ Bt[N,K].
// EPI: 0=f32 out, 1=bf16 out, 2=bf16(bias+relu), 3=f32(bias)
// split-K: Hb=nsplit, sAn=sBn=0, sAh=sBh=K_per_split, sC=M*N.
// ---------------------------------------------------------------------------
template <int EPI>
__global__ __launch_bounds__(256) void gemm_bt(
    const unsigned short* __restrict__ A, int lda, int sAn, int sAh,
    const unsigned short* __restrict__ B, int ldb, int sBn, int sBh,
    void* __restrict__ Cv, int ldc, int sC,
    const float* __restrict__ bias, int nK, int Hb)
{
  __shared__ unsigned short shA[2][8192];
  __shared__ unsigned short shB[2][8192];

  const int z = blockIdx.z;
  const int bn = z / Hb, bh = z % Hb;
  const unsigned short* Ab = A + (size_t)bn * sAn + (size_t)bh * sAh;
  const unsigned short* Bb = B + (size_t)bn * sBn + (size_t)bh * sBh;
  const int m0 = blockIdx.y * 128;
  const int n0 = blockIdx.x * 128;

  const int t = threadIdx.x;
  const int w = t >> 6, l = t & 63;
  const int wr = (w >> 1) * 64, wc = (w & 1) * 64;
  const int lan = l & 15, lgr = l >> 4;

  f32x4 acc[4][4];
#pragma unroll
  for (int m = 0; m < 4; ++m)
#pragma unroll
    for (int n = 0; n < 4; ++n) acc[m][n] = (f32x4){0.f, 0.f, 0.f, 0.f};

  gemm128_2ph(Ab, lda, Bb, ldb, shA, shB, m0, n0, nK, w, l, acc);

  const int zc = z * sC;
#pragma unroll
  for (int m = 0; m < 4; ++m) {
    const int row = m0 + wr + m * 16 + lgr * 4;
#pragma unroll
    for (int n = 0; n < 4; ++n) {
      const int col = n0 + wc + n * 16 + lan;
      const float bcol = (EPI >= 2) ? bias[col] : 0.f;
#pragma unroll
      for (int e = 0; e < 4; ++e) {
        float v = acc[m][n][e];
        const size_t idx = (size_t)zc + (size_t)(row + e) * ldc + col;
        if (EPI == 0) {
          ((float*)Cv)[idx] = v;
        } else if (EPI == 1) {
          ((unsigned short*)Cv)[idx] = f2bf(v);
        } else if (EPI == 2) {
          v += bcol; v = v > 0.f ? v : 0.f;
          ((unsigned short*)Cv)[idx] = f2bf(v);
        } else {
          ((float*)Cv)[idx] = v + bcol;
        }
      }
    }
  }
}

// ---------------------------------------------------------------------------
// Fused projection GEMM: [cat(8192 rows) ; R(256 rows)] @ [Wk|Wv|Wq|Wr]^T
// ---------------------------------------------------------------------------
__global__ __launch_bounds__(256) void gemm_proj(
    const unsigned short* __restrict__ catA, const unsigned short* __restrict__ wt,
    unsigned short* __restrict__ kb, unsigned short* __restrict__ vb,
    unsigned short* __restrict__ qw, unsigned short* __restrict__ qr,
    unsigned short* __restrict__ rb,
    const float* __restrict__ rwb, const float* __restrict__ rrb)
{
  __shared__ unsigned short shA[2][8192];
  __shared__ unsigned short shB[2][8192];

  const int id = blockIdx.x;
  int by, bx;
  if (id < 1024)      { by = id >> 4;               bx = id & 15; }
  else if (id < 1280) { const int u = id - 1024; by = 32 + (u >> 3); bx = 16 + (u & 7); }
  else                { const int u = id - 1280; by = 64 + (u >> 3); bx = 24 + (u & 7); }
  const int m0 = by * 128, n0 = bx * 128;

  const int t = threadIdx.x;
  const int w = t >> 6, l = t & 63;
  const int wr = (w >> 1) * 64, wc = (w & 1) * 64;
  const int lan = l & 15, lgr = l >> 4;

  f32x4 acc[4][4];
#pragma unroll
  for (int m = 0; m < 4; ++m)
#pragma unroll
    for (int n = 0; n < 4; ++n) acc[m][n] = (f32x4){0.f, 0.f, 0.f, 0.f};

  gemm128_2ph(catA, 1024, wt, 1024, shA, shB, m0, n0, 16, w, l, acc);

#pragma unroll
  for (int m = 0; m < 4; ++m) {
    const int row = m0 + wr + m * 16 + lgr * 4;
#pragma unroll
    for (int n = 0; n < 4; ++n) {
      const int col = n0 + wc + n * 16 + lan;
#pragma unroll
      for (int e = 0; e < 4; ++e) {
        const float v = acc[m][n][e];
        const int r = row + e;
        if (col < 1024) {
          kb[(size_t)r * 1024 + col] = f2bf(v);
        } else if (col < 2048) {
          vb[(size_t)r * 1024 + col - 1024] = f2bf(v);
        } else if (col < 3072) {
          const int c = col - 2048;
          const size_t o = (size_t)(r - 4096) * 1024 + c;
          qw[o] = f2bf(v + rwb[c]);
          qr[o] = f2bf(v + rrb[c]);
        } else {
          const int c = col - 3072;
          rb[(size_t)(r - 8192) * 1024 + c] = f2bf(v);
        }
      }
    }
  }
}

// ---------------------------------------------------------------------------
// V transpose: vbf[(j*32+nn)*1024 + hh*64 + d] -> vt[((nn*16+hh)*64+d)*256 + j]
// One block per z=(nn,hh). LDS tile transpose, coalesced 16B reads/writes.
// ---------------------------------------------------------------------------
__global__ __launch_bounds__(256) void vtrans_kernel(
    const unsigned short* __restrict__ V, unsigned short* __restrict__ vt)
{
  __shared__ unsigned short tile[128][72];
  const int z = blockIdx.x;
  const int nn = z >> 4, hh = z & 15;
  const int t = threadIdx.x;
  for (int p = 0; p < 2; ++p) {
    const int j = p * 128 + (t >> 1);
    const int dbase = (t & 1) * 32;
    const unsigned short* src = &V[(size_t)(j * NE + nn) * 1024 + hh * 64 + dbase];
#pragma unroll
    for (int i = 0; i < 4; ++i)
      *(bf16x8*)&tile[t >> 1][dbase + i * 8] = *(const bf16x8*)&src[i * 8];
    __syncthreads();
    const int d = t >> 2, jseg = (t & 3) * 32;
    unsigned short out[32];
#pragma unroll
    for (int jj = 0; jj < 32; ++jj) out[jj] = tile[jseg + jj][d];
    unsigned short* dst = &vt[((size_t)z * 64 + d) * 256 + p * 128 + jseg];
#pragma unroll
    for (int i = 0; i < 4; ++i)
      *(bf16x8*)&dst[i * 8] = *(const bf16x8*)&out[i * 8];
    __syncthreads();
  }
}

// ---------------------------------------------------------------------------
// Fully fused attention: AC + shifted-BD + masked softmax + PV.
// One block per z=(nn,hh), 4 waves, zero barriers (wave-local LDS).
// PV B-fragments now vectorized via vt (V^T copy): one bf16x8 per frag.
// ---------------------------------------------------------------------------
__global__ __launch_bounds__(256) void attn_kernel(
    const unsigned short* __restrict__ qw, const unsigned short* __restrict__ qr,
    const unsigned short* __restrict__ kbf, const unsigned short* __restrict__ rbf,
    const int* __restrict__ ep, const unsigned short* __restrict__ vt,
    unsigned short* __restrict__ O)
{
  __shared__ unsigned short sS[4][32 * 256];   // 64 KB

  const int z = blockIdx.x;
  const int nn = z >> 4, hh = z & 15;
  const int t = threadIdx.x, w = t >> 6, l = t & 63;
  const int lan = l & 15, lgr = l >> 4;
  const int i0 = w * 32;
  unsigned short* S = sS[w];

  // ---- AC = (q + r_w_bias) . K^T  -> S ----
  bf16x8 av[2][2];
#pragma unroll
  for (int m = 0; m < 2; ++m)
#pragma unroll
    for (int kk = 0; kk < 2; ++kk) {
      const int i = i0 + m * 16 + lan;
      av[m][kk] = *(const bf16x8*)&qw[(size_t)(i * NE + nn) * 1024 + hh * 64 + kk * 32 + lgr * 8];
    }
#pragma unroll
  for (int n = 0; n < 16; ++n) {
    bf16x8 bv[2];
#pragma unroll
    for (int kk = 0; kk < 2; ++kk) {
      const int j = n * 16 + lan;
      bv[kk] = *(const bf16x8*)&kbf[(size_t)(j * NE + nn) * 1024 + hh * 64 + kk * 32 + lgr * 8];
    }
#pragma unroll
    for (int m = 0; m < 2; ++m) {
      f32x4 a4 = (f32x4){0.f, 0.f, 0.f, 0.f};
#pragma unroll
      for (int kk = 0; kk < 2; ++kk)
        a4 = __builtin_amdgcn_mfma_f32_16x16x32_bf16(av[m][kk], bv[kk], a4, 0, 0, 0);
#pragma unroll
      for (int e = 0; e < 4; ++e) {
        const int r = m * 16 + lgr * 4 + e;
        const int j = n * 16 + lan;
        const int swz = ((r >> 2) & 3) * 16;
        S[r * 256 + (j ^ swz)] = f2bf(a4[e]);
      }
    }
  }

  // ---- BD = (q + r_r_bias) . R^T, scatter-add with shift j = j' + i - 127 ----
  bf16x8 bq[2][2];
#pragma unroll
  for (int m = 0; m < 2; ++m)
#pragma unroll
    for (int kk = 0; kk < 2; ++kk) {
      const int i = i0 + m * 16 + lan;
      bq[m][kk] = *(const bf16x8*)&qr[(size_t)(i * NE + nn) * 1024 + hh * 64 + kk * 32 + lgr * 8];
    }
#pragma unroll
  for (int n = 0; n < 16; ++n) {
    bf16x8 bv[2];
#pragma unroll
    for (int kk = 0; kk < 2; ++kk) {
      const int jp = n * 16 + lan;
      bv[kk] = *(const bf16x8*)&rbf[(size_t)jp * 1024 + hh * 64 + kk * 32 + lgr * 8];
    }
#pragma unroll
    for (int m = 0; m < 2; ++m) {
      f32x4 a4 = (f32x4){0.f, 0.f, 0.f, 0.f};
#pragma unroll
      for (int kk = 0; kk < 2; ++kk)
        a4 = __builtin_amdgcn_mfma_f32_16x16x32_bf16(bq[m][kk], bv[kk], a4, 0, 0, 0);
#pragma unroll
      for (int e = 0; e < 4; ++e) {
        const int r = m * 16 + lgr * 4 + e;
        const int i = i0 + r;
        const int jp = n * 16 + lan;
        const int j = jp + i - 127;
        if (j >= 0 && j < 256) {
          const int swz = ((r >> 2) & 3) * 16;
          const int idx = r * 256 + (j ^ swz);
          S[idx] = f2bf(bf2f(S[idx]) + a4[e]);
        }
      }
    }
  }

  // ---- masked softmax, in place ----
  const int j0 = l * 4;
  for (int rr = 0; rr < 32; ++rr) {
    const int i = i0 + rr;
    const int epi = ep[i * NE + nn];
    const int swz = ((rr >> 2) & 3) * 16;
    s16x4 s4 = *(const s16x4*)&S[rr * 256 + (j0 ^ swz)];
    float sc[4];
#pragma unroll
    for (int q = 0; q < 4; ++q) {
      const int j = j0 + q;
      bool allow;
      if (j < M_) {
        allow = (epi == 0);
      } else {
        const int jp = j - M_;
        allow = (jp <= i) && (ep[jp * NE + nn] == epi);
      }
      sc[q] = allow ? bf2f((unsigned short)s4[q]) * 0.125f : -1e9f;
    }
    float mx = fmaxf(fmaxf(sc[0], sc[1]), fmaxf(sc[2], sc[3]));
#pragma unroll
    for (int o = 32; o; o >>= 1) mx = fmaxf(mx, __shfl_xor(mx, o));
    float p[4], sum = 0.f;
#pragma unroll
    for (int q = 0; q < 4; ++q) { p[q] = __expf(sc[q] - mx); sum += p[q]; }
#pragma unroll
    for (int o = 32; o; o >>= 1) sum += __shfl_xor(sum, o);
    const float inv = 1.f / sum;
    s16x4 o4;
#pragma unroll
    for (int q = 0; q < 4; ++q) o4[q] = (short)f2bf(p[q] * inv);
    *(s16x4*)&S[rr * 256 + (j0 ^ swz)] = o4;
  }

  // ---- PV: O[i,d] = sum_j P[i,j] * V[j,d], V fragments from vt (16B loads) ----
  const unsigned short* vtz = vt + (size_t)z * 64 * 256;
  f32x4 acc[2][4];
#pragma unroll
  for (int m = 0; m < 2; ++m)
#pragma unroll
    for (int n = 0; n < 4; ++n) acc[m][n] = (f32x4){0.f, 0.f, 0.f, 0.f};

  for (int ks = 0; ks < 8; ++ks) {
    const int kb = ks * 32 + lgr * 8;
    bf16x8 bv2[4];
#pragma unroll
    for (int n = 0; n < 4; ++n) {
      const int d = n * 16 + lan;
      bv2[n] = *(const bf16x8*)&vtz[(size_t)d * 256 + kb];
    }
    bf16x8 pa[2];
#pragma unroll
    for (int m = 0; m < 2; ++m) {
      const int r = m * 16 + lan;
      const int swz = ((r >> 2) & 3) * 16;
      pa[m] = *(const bf16x8*)&S[r * 256 + (kb ^ swz)];
    }
#pragma unroll
    for (int m = 0; m < 2; ++m)
#pragma unroll
      for (int n = 0; n < 4; ++n)
        acc[m][n] = __builtin_amdgcn_mfma_f32_16x16x32_bf16(pa[m], bv2[n], acc[m][n], 0, 0, 0);
  }
#pragma unroll
  for (int m = 0; m < 2; ++m)
#pragma unroll
    for (int n = 0; n < 4; ++n)
#pragma unroll
      for (int e = 0; e < 4; ++e) {
        const int i = i0 + m * 16 + lgr * 4 + e;
        const int d = n * 16 + lan;
        O[(size_t)(i * NE + nn) * 1024 + hh * DH_ + d] = f2bf(acc[m][n][e]);
      }
}

// ---------------------------------------------------------------------------
// Batched weight transpose: 13 slices of 1024x1024 f32 -> bf16 transposed.
// z<5: {Wk,Wv,Wq,Wr,Wo}; z=5..8: W1 col-chunks; z=9..12: W2 row-chunks.
// ---------------------------------------------------------------------------
__global__ __launch_bounds__(256) void transpose13_kernel(
    const float* __restrict__ Wk, const float* __restrict__ Wv,
    const float* __restrict__ Wq, const float* __restrict__ Wr,
    const float* __restrict__ Wo, const float* __restrict__ W1,
    const float* __restrict__ W2,
    unsigned short* __restrict__ wtAll, unsigned short* __restrict__ wto,
    unsigned short* __restrict__ wt1, unsigned short* __restrict__ wt2)
{
  __shared__ float tile[32][33];
  const int zz = blockIdx.z;
  const float* W; unsigned short* WT; int Nd, Kd;
  if (zz < 5) {
    W = (zz == 0) ? Wk : (zz == 1) ? Wv : (zz == 2) ? Wq : (zz == 3) ? Wr : Wo;
    WT = (zz == 4) ? wto : (wtAll + (size_t)zz * 1024 * 1024);
    Nd = 1024; Kd = 1024;
  } else if (zz < 9) {
    const int c = zz - 5;
    W = W1 + (size_t)c * 1024;            // column chunk of [1024][4096]
    WT = wt1 + (size_t)c * 1024 * 1024;   // row chunk of [4096][1024]
    Nd = 4096; Kd = 1024;
  } else {
    const int c = zz - 9;
    W = W2 + (size_t)c * 1024 * 1024;     // row chunk of [4096][1024]
    WT = wt2 + (size_t)c * 1024;          // col chunk of [1024][4096]
    Nd = 1024; Kd = 4096;
  }
  const int tx = threadIdx.x & 31, ty = threadIdx.x >> 5;
  const int nIn = blockIdx.x * 32 + tx;
  const int kBase = blockIdx.y * 32;
#pragma unroll
  for (int r = 0; r < 32; r += 8)
    tile[ty + r][tx] = W[(size_t)(kBase + ty + r) * Nd + nIn];
  __syncthreads();
#pragma unroll
  for (int r = 0; r < 32; r += 8)
    WT[(size_t)(blockIdx.x * 32 + ty + r) * Kd + kBase + tx] = f2bf(tile[tx][ty + r]);
}

__global__ __launch_bounds__(256) void catmem_kernel(
    const float* __restrict__ mems_l, const float* __restrict__ masks,
    unsigned short* __restrict__ cat)
{
  const int idx = blockIdx.x * 256 + threadIdx.x;
  const int d = idx & 1023;
  const int r = idx >> 10;
  const int nn = r & 31, j = r >> 5;
  const float mk0 = masks[nn];
  cat[idx] = f2bf(mems_l[(size_t)(nn * M_ + j) * 1024 + d] * mk0);
}

__global__ __launch_bounds__(256) void hprep_kernel(
    const float* __restrict__ x, const float* __restrict__ ctx,
    float* __restrict__ h, unsigned short* __restrict__ catUp)
{
  const int idx = blockIdx.x * 256 + threadIdx.x;
  const float v = x[idx] + ctx[idx];
  h[idx] = v;
  catUp[idx] = f2bf(v);
}

__global__ __launch_bounds__(256) void rpos_kernel(unsigned short* __restrict__ R)
{
  const int idx = blockIdx.x * 256 + threadIdx.x;
  const int d = idx & 1023, j = idx >> 10;
  const float pos = (float)(KLEN - 1 - j);
  const int f = d & 511;
  const float inv_freq = __expf(-((float)(2 * f) * (1.f / 1024.f)) * 9.210340371976184f);
  const float ang = pos * inv_freq;
  const float v = (d < 512) ? sinf(ang) : cosf(ang);
  R[idx] = f2bf(v);
}

__global__ void ep_kernel(const float* __restrict__ masks, int* __restrict__ ep)
{
  const int nn = threadIdx.x;
  if (nn < NE) {
    int c = 0;
    for (int i = 0; i < T_; ++i) {
      c += (masks[i * NE + nn] == 0.f) ? 1 : 0;
      ep[i * NE + nn] = c;
    }
  }
}

// y = LN(a + sum_{i<NP} parts[i] + bias) * g + b
template <int NP>
__global__ __launch_bounds__(256) void ln_kernel(
    const float* __restrict__ a, const float* __restrict__ parts, size_t pstride,
    const float* __restrict__ bias,
    const float* __restrict__ g, const float* __restrict__ bb,
    float* __restrict__ outf, unsigned short* __restrict__ outbf)
{
  const int row = blockIdx.x;
  const int t = threadIdx.x, w = t >> 6, l = t & 63;
  const int c = t * 4;
  const size_t base = (size_t)row * 1024;
  f32x4 v = *(const f32x4*)&a[base + c];
#pragma unroll
  for (int i = 0; i < NP; ++i)
    v = v + *(const f32x4*)&parts[i * pstride + base + c];
  if (bias) v = v + *(const f32x4*)&bias[c];
  float s = v[0] + v[1] + v[2] + v[3];
#pragma unroll
  for (int o = 32; o; o >>= 1) s += __shfl_xor(s, o);
  __shared__ float red[8];
  if (l == 0) red[w] = s;
  __syncthreads();
  s = red[0] + red[1] + red[2] + red[3];
  const float mu = s * (1.f / 1024.f);
  f32x4 dv = v - mu;
  float s2 = dv[0]*dv[0] + dv[1]*dv[1] + dv[2]*dv[2] + dv[3]*dv[3];
#pragma unroll
  for (int o = 32; o; o >>= 1) s2 += __shfl_xor(s2, o);
  if (l == 0) red[4 + w] = s2;
  __syncthreads();
  s2 = red[4] + red[5] + red[6] + red[7];
  const float inv = rsqrtf(s2 * (1.f / 1024.f) + 1e-5f);
  f32x4 y;
#pragma unroll
  for (int q = 0; q < 4; ++q) y[q] = dv[q] * inv * g[c + q] + bb[c + q];
  *(f32x4*)&outf[base + c] = y;
  if (outbf) {
    s16x4 o4;
#pragma unroll
    for (int q = 0; q < 4; ++q) o4[q] = (short)f2bf(y[q]);
    *(s16x4*)&outbf[base + c] = o4;
  }
}

// ---------------------------------------------------------------------------
extern "C" void kernel_launch(void* const* d_in, const int* in_sizes, int n_in,
                              void* d_out, int out_size, void* d_ws, size_t ws_size,
                              hipStream_t stream)
{
  (void)in_sizes; (void)n_in; (void)out_size; (void)ws_size;
  const float* x    = (const float*)d_in[0];
  const float* ctx  = (const float*)d_in[1];
  const float* mems = (const float*)d_in[2];
  const float* masks= (const float*)d_in[3];
  const float* Wq   = (const float*)d_in[4];
  const float* Wk   = (const float*)d_in[5];
  const float* Wv   = (const float*)d_in[6];
  const float* Wr   = (const float*)d_in[7];
  const float* Wo   = (const float*)d_in[8];
  const float* W1   = (const float*)d_in[9];
  const float* b1   = (const float*)d_in[10];
  const float* W2   = (const float*)d_in[11];
  const float* b2   = (const float*)d_in[12];
  const float* ln1g = (const float*)d_in[13];
  const float* ln1b = (const float*)d_in[14];
  const float* ln2g = (const float*)d_in[15];
  const float* ln2b = (const float*)d_in[16];
  const float* rwb  = (const float*)d_in[17];
  const float* rrb  = (const float*)d_in[18];

  char* ws = (char*)d_ws;
  size_t off = 0;
  auto alloc = [&](size_t bytes) {
    char* p = ws + off;
    off += (bytes + 255) & ~(size_t)255;
    return p;
  };
  unsigned short* wtAll = (unsigned short*)alloc(4096u * 1024 * 2);  // [Wk|Wv|Wq|Wr]^T
  unsigned short* wto = (unsigned short*)alloc(1024u * 1024 * 2);
  unsigned short* wt1 = (unsigned short*)alloc(4096u * 1024 * 2);
  unsigned short* wt2 = (unsigned short*)alloc(4096u * 1024 * 2);
  unsigned short* cat = (unsigned short*)alloc((size_t)(KLEN * NE + 256) * 1024 * 2);
  unsigned short* rbf = (unsigned short*)alloc((size_t)KLEN * 1024 * 2);
  int*            epb = (int*)alloc((size_t)T_ * NE * 4);
  float*          h   = (float*)alloc((size_t)TN * 1024 * 4);
  float*          h1  = (float*)alloc((size_t)TN * 1024 * 4);
  unsigned short* qw  = (unsigned short*)alloc((size_t)TN * 1024 * 2);   // alias: h1_bf
  unsigned short* qr  = (unsigned short*)alloc((size_t)TN * 1024 * 2);
  unsigned short* kbf = (unsigned short*)alloc((size_t)KLEN * NE * 1024 * 2);
  unsigned short* vbf = (unsigned short*)alloc((size_t)KLEN * NE * 1024 * 2);
  unsigned short* vt  = (unsigned short*)alloc((size_t)NB * DH_ * KLEN * 2);
  unsigned short* ACb = (unsigned short*)alloc((size_t)NB * T_ * KLEN * 2); // alias: f1
  unsigned short* BDb = (unsigned short*)alloc((size_t)NB * T_ * KLEN * 2); // part 0,1
  unsigned short* obf = (unsigned short*)alloc((size_t)TN * 1024 * 2);

  unsigned short* catUp = cat + (size_t)M_ * NE * 1024;     // h rows (4096..8191)
  unsigned short* catR  = cat + (size_t)KLEN * NE * 1024;   // R rows (8192..8447)
  unsigned short* f1 = ACb;                 // W1 out
  float* part = (float*)BDb;                // split-K partials (2x TN*1024 f32)
  unsigned short* h1bf = qw;                // qw dead after attn

  rpos_kernel<<<KLEN * 1024 / 256, 256, 0, stream>>>(catR);
  ep_kernel<<<1, 64, 0, stream>>>(masks, epb);
  hprep_kernel<<<TN * 1024 / 256, 256, 0, stream>>>(x, ctx, h, catUp);

  for (int l = 0; l < L_; ++l) {
    const size_t wOff = (size_t)l * 1024 * 1024;
    const size_t wOffBig = (size_t)l * 1024 * 4096;
    transpose13_kernel<<<dim3(32, 32, 13), 256, 0, stream>>>(
        Wk + wOff, Wv + wOff, Wq + wOff, Wr + wOff, Wo + wOff,
        W1 + wOffBig, W2 + wOffBig, wtAll, wto, wt1, wt2);
    catmem_kernel<<<M_ * NE * 1024 / 256, 256, 0, stream>>>(
        mems + (size_t)l * NE * M_ * 1024, masks, cat);

    // fused k|v|q|r projection (1296 blocks, 128^2 tiles, 2-phase)
    gemm_proj<<<1296, 256, 0, stream>>>(cat, wtAll, kbf, vbf, qw, qr, rbf, rwb, rrb);

    // V^T copy for vectorized PV loads
    vtrans_kernel<<<NB, 256, 0, stream>>>(vbf, vt);

    // fully fused attention (scores + rel_shift + masked softmax + PV)
    attn_kernel<<<NB, 256, 0, stream>>>(qw, qr, kbf, rbf, epb, vt, obf);

    // output projection, split-K=2 -> f32 partials; reduce fused into LN1
    gemm_bt<0><<<dim3(8, 32, 2), 256, 0, stream>>>(obf, 1024, 0, 512,
                                                   wto, 1024, 0, 512,
                                                   part, 1024, TN * 1024, nullptr, 8, 2);
    ln_kernel<2><<<TN, 256, 0, stream>>>(h, part, (size_t)TN * 1024, nullptr,
                                         ln1g + l * 1024, ln1b + l * 1024, h1, h1bf);

    // FFN
    gemm_bt<2><<<dim3(32, 32, 1), 256, 0, stream>>>(h1bf, 1024, 0, 0, wt1, 1024, 0, 0,
                                                    f1, 4096, 0, b1 + l * 4096, 16, 1);
    gemm_bt<0><<<dim3(8, 32, 2), 256, 0, stream>>>(f1, 4096, 0, 2048,
                                                   wt2, 4096, 0, 2048,
                                                   part, 1024, TN * 1024, nullptr, 32, 2);
    ln_kernel<2><<<TN, 256, 0, stream>>>(h1, part, (size_t)TN * 1024, b2 + l * 1024,
                                         ln2g + l * 1024, ln2b + l * 1024,
                                         (l == L_ - 1) ? (float*)d_out : h, catUp);
  }
}

// Round 10
// 1885.966 us; speedup vs baseline: 1.0325x; 1.0263x over previous
//
#include <hip/hip_runtime.h>
#include <stdint.h>

#define DEV static __device__ __forceinline__

typedef __attribute__((ext_vector_type(4))) float f32x4;
typedef __attribute__((ext_vector_type(8))) short bf16x8;
typedef __attribute__((ext_vector_type(4))) short s16x4;

// dims
static constexpr int L_ = 6, T_ = 128, NE = 32, D_ = 1024, H_ = 16, DH_ = 64, M_ = 128, DI_ = 4096;
static constexpr int KLEN = M_ + T_;   // 256
static constexpr int TN = T_ * NE;     // 4096
static constexpr int NB = NE * H_;     // 512 attention batches

DEV unsigned short f2bf(float f) {
  unsigned u = __builtin_bit_cast(unsigned, f);
  u += 0x7FFFu + ((u >> 16) & 1u);
  return (unsigned short)(u >> 16);
}
DEV float bf2f(unsigned short h) {
  unsigned u = ((unsigned)h) << 16;
  return __builtin_bit_cast(float, u);
}

DEV void gload16(const unsigned short* g, unsigned short* lds) {
  __builtin_amdgcn_global_load_lds(
      (const __attribute__((address_space(1))) unsigned int*)g,
      (__attribute__((address_space(3))) unsigned int*)lds, 16, 0, 0);
}

#define WAITV0 asm volatile("s_waitcnt vmcnt(0)" ::: "memory")

// ---------------------------------------------------------------------------
// 128x128 tile core, BK=64, 4 waves (2x2). T2 XOR-swizzle, 2-phase.
// ---------------------------------------------------------------------------
DEV void stage128(const unsigned short* __restrict__ Ab, int lda,
                  const unsigned short* __restrict__ Bb, int ldb,
                  unsigned short* lA, unsigned short* lB,
                  int m0, int n0, int k0, int w, int l)
{
#pragma unroll
  for (int i = 0; i < 4; ++i) {
    const int obb = i * 4096 + w * 1024;
    const int ob  = obb + (l << 4);
    const int row = ob >> 7;
    const int col = (((ob >> 4) & 7) ^ (row & 7)) << 3;
    gload16(Ab + (size_t)(m0 + row) * lda + k0 + col, lA + (obb >> 1));
    gload16(Bb + (size_t)(n0 + row) * ldb + k0 + col, lB + (obb >> 1));
  }
}

DEV void compute128(const unsigned short* lA, const unsigned short* lB,
                    int w, int l, f32x4 acc[4][4])
{
  const int wr = (w >> 1) * 64, wc = (w & 1) * 64;
  const int lan = l & 15, lgr = l >> 4;
#pragma unroll
  for (int ks = 0; ks < 2; ++ks) {
    bf16x8 av[4], bv[4];
#pragma unroll
    for (int m = 0; m < 4; ++m) {
      const int row = wr + m * 16 + lan;
      const int byte = ((row << 7) + (ks << 6) + (lgr << 4)) ^ ((row & 7) << 4);
      av[m] = *(const bf16x8*)((const char*)lA + byte);
    }
#pragma unroll
    for (int n = 0; n < 4; ++n) {
      const int row = wc + n * 16 + lan;
      const int byte = ((row << 7) + (ks << 6) + (lgr << 4)) ^ ((row & 7) << 4);
      bv[n] = *(const bf16x8*)((const char*)lB + byte);
    }
#pragma unroll
    for (int m = 0; m < 4; ++m)
#pragma unroll
      for (int n = 0; n < 4; ++n)
        acc[m][n] = __builtin_amdgcn_mfma_f32_16x16x32_bf16(av[m], bv[n], acc[m][n], 0, 0, 0);
  }
}

DEV void gemm128_2ph(const unsigned short* __restrict__ Ab, int lda,
                     const unsigned short* __restrict__ Bb, int ldb,
                     unsigned short (*shA)[8192], unsigned short (*shB)[8192],
                     int m0, int n0, int nK, int w, int l, f32x4 acc[4][4])
{
  stage128(Ab, lda, Bb, ldb, shA[0], shB[0], m0, n0, 0, w, l);
  WAITV0;
  __syncthreads();
  int cur = 0;
  for (int kt = 0; kt < nK; ++kt) {
    if (kt + 1 < nK)
      stage128(Ab, lda, Bb, ldb, shA[cur ^ 1], shB[cur ^ 1], m0, n0, (kt + 1) * 64, w, l);
    compute128(shA[cur], shB[cur], w, l, acc);
    WAITV0;
    __syncthreads();
    cur ^= 1;
  }
}

// ---------------------------------------------------------------------------
// Generic batched GEMM: C[M,N] = A[M,K] @ Bt[N,K].  1D grid of gx*gy*nz
// blocks with (a) bijective XCD-chunk swizzle (nwg%8==0) and (b) group-of-8
// 2D decode so each XCD's concurrent blocks form an ~8x8 tile rectangle
// (working set ~4 MB = one XCD L2).  gx must be a multiple of 8.
// EPI: 0=f32 out, 1=bf16 out, 2=bf16(bias+relu)
// split-K: Hb=nsplit, sAn=sBn=0, sAh=sBh=K_per_split, sC=M*N.
// ---------------------------------------------------------------------------
template <int EPI>
__global__ __launch_bounds__(256) void gemm_bt(
    const unsigned short* __restrict__ A, int lda, int sAn, int sAh,
    const unsigned short* __restrict__ B, int ldb, int sBn, int sBh,
    void* __restrict__ Cv, int ldc, int sC,
    const float* __restrict__ bias, int nK, int Hb, int gx, int gy)
{
  __shared__ unsigned short shA[2][8192];
  __shared__ unsigned short shB[2][8192];

  // T1 XCD swizzle + group-8 decode
  const int nwg = gridDim.x;
  const int bid = blockIdx.x;
  const int id = (bid & 7) * (nwg >> 3) + (bid >> 3);
  const int pg = gx * gy;
  const int z = id / pg;
  const int rem = id - z * pg;
  const int sc = rem / (gy * 8);
  const int within = rem - sc * (gy * 8);
  const int by = within >> 3;
  const int bx = sc * 8 + (within & 7);

  const int bn = z / Hb, bh = z % Hb;
  const unsigned short* Ab = A + (size_t)bn * sAn + (size_t)bh * sAh;
  const unsigned short* Bb = B + (size_t)bn * sBn + (size_t)bh * sBh;
  const int m0 = by * 128;
  const int n0 = bx * 128;

  const int t = threadIdx.x;
  const int w = t >> 6, l = t & 63;
  const int wr = (w >> 1) * 64, wc = (w & 1) * 64;
  const int lan = l & 15, lgr = l >> 4;

  f32x4 acc[4][4];
#pragma unroll
  for (int m = 0; m < 4; ++m)
#pragma unroll
    for (int n = 0; n < 4; ++n) acc[m][n] = (f32x4){0.f, 0.f, 0.f, 0.f};

  gemm128_2ph(Ab, lda, Bb, ldb, shA, shB, m0, n0, nK, w, l, acc);

  const int zc = z * sC;
#pragma unroll
  for (int m = 0; m < 4; ++m) {
    const int row = m0 + wr + m * 16 + lgr * 4;
#pragma unroll
    for (int n = 0; n < 4; ++n) {
      const int col = n0 + wc + n * 16 + lan;
      const float bcol = (EPI >= 2) ? bias[col] : 0.f;
#pragma unroll
      for (int e = 0; e < 4; ++e) {
        float v = acc[m][n][e];
        const size_t idx = (size_t)zc + (size_t)(row + e) * ldc + col;
        if (EPI == 0) {
          ((float*)Cv)[idx] = v;
        } else if (EPI == 1) {
          ((unsigned short*)Cv)[idx] = f2bf(v);
        } else {
          v += bcol; v = v > 0.f ? v : 0.f;
          ((unsigned short*)Cv)[idx] = f2bf(v);
        }
      }
    }
  }
}

// ---------------------------------------------------------------------------
// Fused projection GEMM: [cat(8192 rows) ; R(256 rows)] @ [Wk|Wv|Wq|Wr]^T
// 1296 blocks = 8 XCD-chunks x 162; kv region uses group-8 decode.
// ---------------------------------------------------------------------------
__global__ __launch_bounds__(256) void gemm_proj(
    const unsigned short* __restrict__ catA, const unsigned short* __restrict__ wt,
    unsigned short* __restrict__ kb, unsigned short* __restrict__ vb,
    unsigned short* __restrict__ qw, unsigned short* __restrict__ qr,
    unsigned short* __restrict__ rb,
    const float* __restrict__ rwb, const float* __restrict__ rrb)
{
  __shared__ unsigned short shA[2][8192];
  __shared__ unsigned short shB[2][8192];

  const int bid = blockIdx.x;
  const int id = (bid & 7) * 162 + (bid >> 3);   // bijective: 1296 = 8*162
  int by, bx;
  if (id < 1024) {                // kv region: 64 by x 16 bx, group-8
    const int sc = id >> 9;                      // 2 super-cols of 8 bx
    const int within = id & 511;
    by = within >> 3;
    bx = sc * 8 + (within & 7);
  } else if (id < 1280) {         // q region: 32 by x 8 bx (already group-8)
    const int u = id - 1024;
    by = 32 + (u >> 3); bx = 16 + (u & 7);
  } else {                        // r region
    const int u = id - 1280;
    by = 64 + (u >> 3); bx = 24 + (u & 7);
  }
  const int m0 = by * 128, n0 = bx * 128;

  const int t = threadIdx.x;
  const int w = t >> 6, l = t & 63;
  const int wr = (w >> 1) * 64, wc = (w & 1) * 64;
  const int lan = l & 15, lgr = l >> 4;

  f32x4 acc[4][4];
#pragma unroll
  for (int m = 0; m < 4; ++m)
#pragma unroll
    for (int n = 0; n < 4; ++n) acc[m][n] = (f32x4){0.f, 0.f, 0.f, 0.f};

  gemm128_2ph(catA, 1024, wt, 1024, shA, shB, m0, n0, 16, w, l, acc);

#pragma unroll
  for (int m = 0; m < 4; ++m) {
    const int row = m0 + wr + m * 16 + lgr * 4;
#pragma unroll
    for (int n = 0; n < 4; ++n) {
      const int col = n0 + wc + n * 16 + lan;
#pragma unroll
      for (int e = 0; e < 4; ++e) {
        const float v = acc[m][n][e];
        const int r = row + e;
        if (col < 1024) {
          kb[(size_t)r * 1024 + col] = f2bf(v);
        } else if (col < 2048) {
          vb[(size_t)r * 1024 + col - 1024] = f2bf(v);
        } else if (col < 3072) {
          const int c = col - 2048;
          const size_t o = (size_t)(r - 4096) * 1024 + c;
          qw[o] = f2bf(v + rwb[c]);
          qr[o] = f2bf(v + rrb[c]);
        } else {
          const int c = col - 3072;
          rb[(size_t)(r - 8192) * 1024 + c] = f2bf(v);
        }
      }
    }
  }
}

// ---------------------------------------------------------------------------
// Fully fused attention: AC + shifted-BD + masked softmax + PV.
// One block per z=(nn,hh), 4 waves, zero barriers (wave-local LDS).
// ---------------------------------------------------------------------------
__global__ __launch_bounds__(256) void attn_kernel(
    const unsigned short* __restrict__ qw, const unsigned short* __restrict__ qr,
    const unsigned short* __restrict__ kbf, const unsigned short* __restrict__ rbf,
    const int* __restrict__ ep, const unsigned short* __restrict__ V,
    unsigned short* __restrict__ O)
{
  __shared__ unsigned short sS[4][32 * 256];   // 64 KB

  const int z = blockIdx.x;
  const int nn = z >> 4, hh = z & 15;
  const int t = threadIdx.x, w = t >> 6, l = t & 63;
  const int lan = l & 15, lgr = l >> 4;
  const int i0 = w * 32;
  unsigned short* S = sS[w];

  // ---- AC = (q + r_w_bias) . K^T  -> S ----
  bf16x8 av[2][2];
#pragma unroll
  for (int m = 0; m < 2; ++m)
#pragma unroll
    for (int kk = 0; kk < 2; ++kk) {
      const int i = i0 + m * 16 + lan;
      av[m][kk] = *(const bf16x8*)&qw[(size_t)(i * NE + nn) * 1024 + hh * 64 + kk * 32 + lgr * 8];
    }
#pragma unroll
  for (int n = 0; n < 16; ++n) {
    bf16x8 bv[2];
#pragma unroll
    for (int kk = 0; kk < 2; ++kk) {
      const int j = n * 16 + lan;
      bv[kk] = *(const bf16x8*)&kbf[(size_t)(j * NE + nn) * 1024 + hh * 64 + kk * 32 + lgr * 8];
    }
#pragma unroll
    for (int m = 0; m < 2; ++m) {
      f32x4 a4 = (f32x4){0.f, 0.f, 0.f, 0.f};
#pragma unroll
      for (int kk = 0; kk < 2; ++kk)
        a4 = __builtin_amdgcn_mfma_f32_16x16x32_bf16(av[m][kk], bv[kk], a4, 0, 0, 0);
#pragma unroll
      for (int e = 0; e < 4; ++e) {
        const int r = m * 16 + lgr * 4 + e;
        const int j = n * 16 + lan;
        const int swz = ((r >> 2) & 3) * 16;
        S[r * 256 + (j ^ swz)] = f2bf(a4[e]);
      }
    }
  }

  // ---- BD = (q + r_r_bias) . R^T, scatter-add with shift j = j' + i - 127 ----
  bf16x8 bq[2][2];
#pragma unroll
  for (int m = 0; m < 2; ++m)
#pragma unroll
    for (int kk = 0; kk < 2; ++kk) {
      const int i = i0 + m * 16 + lan;
      bq[m][kk] = *(const bf16x8*)&qr[(size_t)(i * NE + nn) * 1024 + hh * 64 + kk * 32 + lgr * 8];
    }
#pragma unroll
  for (int n = 0; n < 16; ++n) {
    bf16x8 bv[2];
#pragma unroll
    for (int kk = 0; kk < 2; ++kk) {
      const int jp = n * 16 + lan;
      bv[kk] = *(const bf16x8*)&rbf[(size_t)jp * 1024 + hh * 64 + kk * 32 + lgr * 8];
    }
#pragma unroll
    for (int m = 0; m < 2; ++m) {
      f32x4 a4 = (f32x4){0.f, 0.f, 0.f, 0.f};
#pragma unroll
      for (int kk = 0; kk < 2; ++kk)
        a4 = __builtin_amdgcn_mfma_f32_16x16x32_bf16(bq[m][kk], bv[kk], a4, 0, 0, 0);
#pragma unroll
      for (int e = 0; e < 4; ++e) {
        const int r = m * 16 + lgr * 4 + e;
        const int i = i0 + r;
        const int jp = n * 16 + lan;
        const int j = jp + i - 127;
        if (j >= 0 && j < 256) {
          const int swz = ((r >> 2) & 3) * 16;
          const int idx = r * 256 + (j ^ swz);
          S[idx] = f2bf(bf2f(S[idx]) + a4[e]);
        }
      }
    }
  }

  // ---- masked softmax, in place ----
  const int j0 = l * 4;
  for (int rr = 0; rr < 32; ++rr) {
    const int i = i0 + rr;
    const int epi = ep[i * NE + nn];
    const int swz = ((rr >> 2) & 3) * 16;
    s16x4 s4 = *(const s16x4*)&S[rr * 256 + (j0 ^ swz)];
    float sc[4];
#pragma unroll
    for (int q = 0; q < 4; ++q) {
      const int j = j0 + q;
      bool allow;
      if (j < M_) {
        allow = (epi == 0);
      } else {
        const int jp = j - M_;
        allow = (jp <= i) && (ep[jp * NE + nn] == epi);
      }
      sc[q] = allow ? bf2f((unsigned short)s4[q]) * 0.125f : -1e9f;
    }
    float mx = fmaxf(fmaxf(sc[0], sc[1]), fmaxf(sc[2], sc[3]));
#pragma unroll
    for (int o = 32; o; o >>= 1) mx = fmaxf(mx, __shfl_xor(mx, o));
    float p[4], sum = 0.f;
#pragma unroll
    for (int q = 0; q < 4; ++q) { p[q] = __expf(sc[q] - mx); sum += p[q]; }
#pragma unroll
    for (int o = 32; o; o >>= 1) sum += __shfl_xor(sum, o);
    const float inv = 1.f / sum;
    s16x4 o4;
#pragma unroll
    for (int q = 0; q < 4; ++q) o4[q] = (short)f2bf(p[q] * inv);
    *(s16x4*)&S[rr * 256 + (j0 ^ swz)] = o4;
  }

  // ---- PV ----
  const unsigned short* Vz = V + hh * DH_;
  f32x4 acc[2][4];
#pragma unroll
  for (int m = 0; m < 2; ++m)
#pragma unroll
    for (int n = 0; n < 4; ++n) acc[m][n] = (f32x4){0.f, 0.f, 0.f, 0.f};

  for (int ks = 0; ks < 8; ++ks) {
    const int kb = ks * 32 + lgr * 8;
    bf16x8 bv2[4];
#pragma unroll
    for (int n = 0; n < 4; ++n) {
      const int d = n * 16 + lan;
      bf16x8 tmp;
#pragma unroll
      for (int jj = 0; jj < 8; ++jj)
        tmp[jj] = (short)Vz[(size_t)((kb + jj) * NE + nn) * 1024 + d];
      bv2[n] = tmp;
    }
    bf16x8 pa[2];
#pragma unroll
    for (int m = 0; m < 2; ++m) {
      const int r = m * 16 + lan;
      const int swz = ((r >> 2) & 3) * 16;
      pa[m] = *(const bf16x8*)&S[r * 256 + (kb ^ swz)];
    }
#pragma unroll
    for (int m = 0; m < 2; ++m)
#pragma unroll
      for (int n = 0; n < 4; ++n)
        acc[m][n] = __builtin_amdgcn_mfma_f32_16x16x32_bf16(pa[m], bv2[n], acc[m][n], 0, 0, 0);
  }
#pragma unroll
  for (int m = 0; m < 2; ++m)
#pragma unroll
    for (int n = 0; n < 4; ++n)
#pragma unroll
      for (int e = 0; e < 4; ++e) {
        const int i = i0 + m * 16 + lgr * 4 + e;
        const int d = n * 16 + lan;
        O[(size_t)(i * NE + nn) * 1024 + hh * DH_ + d] = f2bf(acc[m][n][e]);
      }
}

// ---------------------------------------------------------------------------
// Batched weight transpose: 13 slices of 1024x1024 f32 -> bf16 transposed.
// z<5: {Wk,Wv,Wq,Wr,Wo}; z=5..8: W1 col-chunks; z=9..12: W2 row-chunks.
// ---------------------------------------------------------------------------
__global__ __launch_bounds__(256) void transpose13_kernel(
    const float* __restrict__ Wk, const float* __restrict__ Wv,
    const float* __restrict__ Wq, const float* __restrict__ Wr,
    const float* __restrict__ Wo, const float* __restrict__ W1,
    const float* __restrict__ W2,
    unsigned short* __restrict__ wtAll, unsigned short* __restrict__ wto,
    unsigned short* __restrict__ wt1, unsigned short* __restrict__ wt2)
{
  __shared__ float tile[32][33];
  const int zz = blockIdx.z;
  const float* W; unsigned short* WT; int Nd, Kd;
  if (zz < 5) {
    W = (zz == 0) ? Wk : (zz == 1) ? Wv : (zz == 2) ? Wq : (zz == 3) ? Wr : Wo;
    WT = (zz == 4) ? wto : (wtAll + (size_t)zz * 1024 * 1024);
    Nd = 1024; Kd = 1024;
  } else if (zz < 9) {
    const int c = zz - 5;
    W = W1 + (size_t)c * 1024;            // column chunk of [1024][4096]
    WT = wt1 + (size_t)c * 1024 * 1024;   // row chunk of [4096][1024]
    Nd = 4096; Kd = 1024;
  } else {
    const int c = zz - 9;
    W = W2 + (size_t)c * 1024 * 1024;     // row chunk of [4096][1024]
    WT = wt2 + (size_t)c * 1024;          // col chunk of [1024][4096]
    Nd = 1024; Kd = 4096;
  }
  const int tx = threadIdx.x & 31, ty = threadIdx.x >> 5;
  const int nIn = blockIdx.x * 32 + tx;
  const int kBase = blockIdx.y * 32;
#pragma unroll
  for (int r = 0; r < 32; r += 8)
    tile[ty + r][tx] = W[(size_t)(kBase + ty + r) * Nd + nIn];
  __syncthreads();
#pragma unroll
  for (int r = 0; r < 32; r += 8)
    WT[(size_t)(blockIdx.x * 32 + ty + r) * Kd + kBase + tx] = f2bf(tile[tx][ty + r]);
}

__global__ __launch_bounds__(256) void catmem_kernel(
    const float* __restrict__ mems_l, const float* __restrict__ masks,
    unsigned short* __restrict__ cat)
{
  const int idx = blockIdx.x * 256 + threadIdx.x;
  const int d = idx & 1023;
  const int r = idx >> 10;
  const int nn = r & 31, j = r >> 5;
  const float mk0 = masks[nn];
  cat[idx] = f2bf(mems_l[(size_t)(nn * M_ + j) * 1024 + d] * mk0);
}

__global__ __launch_bounds__(256) void hprep_kernel(
    const float* __restrict__ x, const float* __restrict__ ctx,
    float* __restrict__ h, unsigned short* __restrict__ catUp)
{
  const int idx = blockIdx.x * 256 + threadIdx.x;
  const float v = x[idx] + ctx[idx];
  h[idx] = v;
  catUp[idx] = f2bf(v);
}

__global__ __launch_bounds__(256) void rpos_kernel(unsigned short* __restrict__ R)
{
  const int idx = blockIdx.x * 256 + threadIdx.x;
  const int d = idx & 1023, j = idx >> 10;
  const float pos = (float)(KLEN - 1 - j);
  const int f = d & 511;
  const float inv_freq = __expf(-((float)(2 * f) * (1.f / 1024.f)) * 9.210340371976184f);
  const float ang = pos * inv_freq;
  const float v = (d < 512) ? sinf(ang) : cosf(ang);
  R[idx] = f2bf(v);
}

__global__ void ep_kernel(const float* __restrict__ masks, int* __restrict__ ep)
{
  const int nn = threadIdx.x;
  if (nn < NE) {
    int c = 0;
    for (int i = 0; i < T_; ++i) {
      c += (masks[i * NE + nn] == 0.f) ? 1 : 0;
      ep[i * NE + nn] = c;
    }
  }
}

// y = LN(a + sum_{i<NP} parts[i] + bias) * g + b
template <int NP>
__global__ __launch_bounds__(256) void ln_kernel(
    const float* __restrict__ a, const float* __restrict__ parts, size_t pstride,
    const float* __restrict__ bias,
    const float* __restrict__ g, const float* __restrict__ bb,
    float* __restrict__ outf, unsigned short* __restrict__ outbf)
{
  const int row = blockIdx.x;
  const int t = threadIdx.x, w = t >> 6, l = t & 63;
  const int c = t * 4;
  const size_t base = (size_t)row * 1024;
  f32x4 v = *(const f32x4*)&a[base + c];
#pragma unroll
  for (int i = 0; i < NP; ++i)
    v = v + *(const f32x4*)&parts[i * pstride + base + c];
  if (bias) v = v + *(const f32x4*)&bias[c];
  float s = v[0] + v[1] + v[2] + v[3];
#pragma unroll
  for (int o = 32; o; o >>= 1) s += __shfl_xor(s, o);
  __shared__ float red[8];
  if (l == 0) red[w] = s;
  __syncthreads();
  s = red[0] + red[1] + red[2] + red[3];
  const float mu = s * (1.f / 1024.f);
  f32x4 dv = v - mu;
  float s2 = dv[0]*dv[0] + dv[1]*dv[1] + dv[2]*dv[2] + dv[3]*dv[3];
#pragma unroll
  for (int o = 32; o; o >>= 1) s2 += __shfl_xor(s2, o);
  if (l == 0) red[4 + w] = s2;
  __syncthreads();
  s2 = red[4] + red[5] + red[6] + red[7];
  const float inv = rsqrtf(s2 * (1.f / 1024.f) + 1e-5f);
  f32x4 y;
#pragma unroll
  for (int q = 0; q < 4; ++q) y[q] = dv[q] * inv * g[c + q] + bb[c + q];
  *(f32x4*)&outf[base + c] = y;
  if (outbf) {
    s16x4 o4;
#pragma unroll
    for (int q = 0; q < 4; ++q) o4[q] = (short)f2bf(y[q]);
    *(s16x4*)&outbf[base + c] = o4;
  }
}

// ---------------------------------------------------------------------------
extern "C" void kernel_launch(void* const* d_in, const int* in_sizes, int n_in,
                              void* d_out, int out_size, void* d_ws, size_t ws_size,
                              hipStream_t stream)
{
  (void)in_sizes; (void)n_in; (void)out_size; (void)ws_size;
  const float* x    = (const float*)d_in[0];
  const float* ctx  = (const float*)d_in[1];
  const float* mems = (const float*)d_in[2];
  const float* masks= (const float*)d_in[3];
  const float* Wq   = (const float*)d_in[4];
  const float* Wk   = (const float*)d_in[5];
  const float* Wv   = (const float*)d_in[6];
  const float* Wr   = (const float*)d_in[7];
  const float* Wo   = (const float*)d_in[8];
  const float* W1   = (const float*)d_in[9];
  const float* b1   = (const float*)d_in[10];
  const float* W2   = (const float*)d_in[11];
  const float* b2   = (const float*)d_in[12];
  const float* ln1g = (const float*)d_in[13];
  const float* ln1b = (const float*)d_in[14];
  const float* ln2g = (const float*)d_in[15];
  const float* ln2b = (const float*)d_in[16];
  const float* rwb  = (const float*)d_in[17];
  const float* rrb  = (const float*)d_in[18];

  char* ws = (char*)d_ws;
  size_t off = 0;
  auto alloc = [&](size_t bytes) {
    char* p = ws + off;
    off += (bytes + 255) & ~(size_t)255;
    return p;
  };
  unsigned short* wtAll = (unsigned short*)alloc(4096u * 1024 * 2);  // [Wk|Wv|Wq|Wr]^T
  unsigned short* wto = (unsigned short*)alloc(1024u * 1024 * 2);
  unsigned short* wt1 = (unsigned short*)alloc(4096u * 1024 * 2);
  unsigned short* wt2 = (unsigned short*)alloc(4096u * 1024 * 2);
  unsigned short* cat = (unsigned short*)alloc((size_t)(KLEN * NE + 256) * 1024 * 2);
  unsigned short* rbf = (unsigned short*)alloc((size_t)KLEN * 1024 * 2);
  int*            epb = (int*)alloc((size_t)T_ * NE * 4);
  float*          h   = (float*)alloc((size_t)TN * 1024 * 4);
  float*          h1  = (float*)alloc((size_t)TN * 1024 * 4);
  unsigned short* qw  = (unsigned short*)alloc((size_t)TN * 1024 * 2);   // alias: h1_bf
  unsigned short* qr  = (unsigned short*)alloc((size_t)TN * 1024 * 2);
  unsigned short* kbf = (unsigned short*)alloc((size_t)KLEN * NE * 1024 * 2);
  unsigned short* vbf = (unsigned short*)alloc((size_t)KLEN * NE * 1024 * 2);
  unsigned short* ACb = (unsigned short*)alloc((size_t)NB * T_ * KLEN * 2); // alias: f1
  unsigned short* BDb = (unsigned short*)alloc((size_t)NB * T_ * KLEN * 2); // part 0,1
  unsigned short* obf = (unsigned short*)alloc((size_t)TN * 1024 * 2);

  unsigned short* catUp = cat + (size_t)M_ * NE * 1024;     // h rows (4096..8191)
  unsigned short* catR  = cat + (size_t)KLEN * NE * 1024;   // R rows (8192..8447)
  unsigned short* f1 = ACb;                 // W1 out
  float* part = (float*)BDb;                // split-K partials (2x TN*1024 f32)
  unsigned short* h1bf = qw;                // qw dead after attn

  rpos_kernel<<<KLEN * 1024 / 256, 256, 0, stream>>>(catR);
  ep_kernel<<<1, 64, 0, stream>>>(masks, epb);
  hprep_kernel<<<TN * 1024 / 256, 256, 0, stream>>>(x, ctx, h, catUp);

  for (int l = 0; l < L_; ++l) {
    const size_t wOff = (size_t)l * 1024 * 1024;
    const size_t wOffBig = (size_t)l * 1024 * 4096;
    transpose13_kernel<<<dim3(32, 32, 13), 256, 0, stream>>>(
        Wk + wOff, Wv + wOff, Wq + wOff, Wr + wOff, Wo + wOff,
        W1 + wOffBig, W2 + wOffBig, wtAll, wto, wt1, wt2);
    catmem_kernel<<<M_ * NE * 1024 / 256, 256, 0, stream>>>(
        mems + (size_t)l * NE * M_ * 1024, masks, cat);

    // fused k|v|q|r projection (1296 blocks, XCD-swizzled)
    gemm_proj<<<1296, 256, 0, stream>>>(cat, wtAll, kbf, vbf, qw, qr, rbf, rwb, rrb);

    // fully fused attention (scores + rel_shift + masked softmax + PV)
    attn_kernel<<<NB, 256, 0, stream>>>(qw, qr, kbf, rbf, epb, vbf, obf);

    // output projection, split-K=2 -> f32 partials; reduce fused into LN1
    gemm_bt<0><<<512, 256, 0, stream>>>(obf, 1024, 0, 512,
                                        wto, 1024, 0, 512,
                                        part, 1024, TN * 1024, nullptr, 8, 2, 8, 32);
    ln_kernel<2><<<TN, 256, 0, stream>>>(h, part, (size_t)TN * 1024, nullptr,
                                         ln1g + l * 1024, ln1b + l * 1024, h1, h1bf);

    // FFN
    gemm_bt<2><<<1024, 256, 0, stream>>>(h1bf, 1024, 0, 0, wt1, 1024, 0, 0,
                                         f1, 4096, 0, b1 + l * 4096, 16, 1, 32, 32);
    gemm_bt<0><<<512, 256, 0, stream>>>(f1, 4096, 0, 2048,
                                        wt2, 4096, 0, 2048,
                                        part, 1024, TN * 1024, nullptr, 32, 2, 8, 32);
    ln_kernel<2><<<TN, 256, 0, stream>>>(h1, part, (size_t)TN * 1024, b2 + l * 1024,
                                         ln2g + l * 1024, ln2b + l * 1024,
                                         (l == L_ - 1) ? (float*)d_out : h, catUp);
  }
}

// Round 11
// 1805.826 us; speedup vs baseline: 1.0783x; 1.0444x over previous
//
#include <hip/hip_runtime.h>
#include <stdint.h>

#define DEV static __device__ __forceinline__

typedef __attribute__((ext_vector_type(4))) float f32x4;
typedef __attribute__((ext_vector_type(8))) short bf16x8;
typedef __attribute__((ext_vector_type(4))) short s16x4;

// dims
static constexpr int L_ = 6, T_ = 128, NE = 32, D_ = 1024, H_ = 16, DH_ = 64, M_ = 128, DI_ = 4096;
static constexpr int KLEN = M_ + T_;   // 256
static constexpr int TN = T_ * NE;     // 4096
static constexpr int NB = NE * H_;     // 512 attention batches

DEV unsigned short f2bf(float f) {
  unsigned u = __builtin_bit_cast(unsigned, f);
  u += 0x7FFFu + ((u >> 16) & 1u);
  return (unsigned short)(u >> 16);
}
DEV float bf2f(unsigned short h) {
  unsigned u = ((unsigned)h) << 16;
  return __builtin_bit_cast(float, u);
}

DEV void gload16(const unsigned short* g, unsigned short* lds) {
  __builtin_amdgcn_global_load_lds(
      (const __attribute__((address_space(1))) unsigned int*)g,
      (__attribute__((address_space(3))) unsigned int*)lds, 16, 0, 0);
}

#define WAITV0 asm volatile("s_waitcnt vmcnt(0)" ::: "memory")

// ---------------------------------------------------------------------------
// 128x128 tile core, BK=64, 4 waves (2x2). T2 XOR-swizzle, 2-phase.
// ---------------------------------------------------------------------------
DEV void stage128(const unsigned short* __restrict__ Ab, int lda,
                  const unsigned short* __restrict__ Bb, int ldb,
                  unsigned short* lA, unsigned short* lB,
                  int m0, int n0, int k0, int w, int l)
{
#pragma unroll
  for (int i = 0; i < 4; ++i) {
    const int obb = i * 4096 + w * 1024;
    const int ob  = obb + (l << 4);
    const int row = ob >> 7;
    const int col = (((ob >> 4) & 7) ^ (row & 7)) << 3;
    gload16(Ab + (size_t)(m0 + row) * lda + k0 + col, lA + (obb >> 1));
    gload16(Bb + (size_t)(n0 + row) * ldb + k0 + col, lB + (obb >> 1));
  }
}

DEV void compute128(const unsigned short* lA, const unsigned short* lB,
                    int w, int l, f32x4 acc[4][4])
{
  const int wr = (w >> 1) * 64, wc = (w & 1) * 64;
  const int lan = l & 15, lgr = l >> 4;
#pragma unroll
  for (int ks = 0; ks < 2; ++ks) {
    bf16x8 av[4], bv[4];
#pragma unroll
    for (int m = 0; m < 4; ++m) {
      const int row = wr + m * 16 + lan;
      const int byte = ((row << 7) + (ks << 6) + (lgr << 4)) ^ ((row & 7) << 4);
      av[m] = *(const bf16x8*)((const char*)lA + byte);
    }
#pragma unroll
    for (int n = 0; n < 4; ++n) {
      const int row = wc + n * 16 + lan;
      const int byte = ((row << 7) + (ks << 6) + (lgr << 4)) ^ ((row & 7) << 4);
      bv[n] = *(const bf16x8*)((const char*)lB + byte);
    }
#pragma unroll
    for (int m = 0; m < 4; ++m)
#pragma unroll
      for (int n = 0; n < 4; ++n)
        acc[m][n] = __builtin_amdgcn_mfma_f32_16x16x32_bf16(av[m], bv[n], acc[m][n], 0, 0, 0);
  }
}

DEV void gemm128_2ph(const unsigned short* __restrict__ Ab, int lda,
                     const unsigned short* __restrict__ Bb, int ldb,
                     unsigned short (*shA)[8192], unsigned short (*shB)[8192],
                     int m0, int n0, int nK, int w, int l, f32x4 acc[4][4])
{
  stage128(Ab, lda, Bb, ldb, shA[0], shB[0], m0, n0, 0, w, l);
  WAITV0;
  __syncthreads();
  int cur = 0;
  for (int kt = 0; kt < nK; ++kt) {
    if (kt + 1 < nK)
      stage128(Ab, lda, Bb, ldb, shA[cur ^ 1], shB[cur ^ 1], m0, n0, (kt + 1) * 64, w, l);
    compute128(shA[cur], shB[cur], w, l, acc);
    WAITV0;
    __syncthreads();
    cur ^= 1;
  }
}

// ---------------------------------------------------------------------------
// Generic batched GEMM: C[M,N] = A[M,K] @ Bt[N,K].  1D grid, bijective
// XCD-chunk swizzle + group-of-8 2D decode (L2 locality; kept — it won for
// W1/W2/o-proj in R10). gx multiple of 8.
// EPI: 0=f32 out, 1=bf16 out, 2=bf16(bias+relu)
// split-K: Hb=nsplit, sAn=sBn=0, sAh=sBh=K_per_split, sC=M*N.
// ---------------------------------------------------------------------------
template <int EPI>
__global__ __launch_bounds__(256) void gemm_bt(
    const unsigned short* __restrict__ A, int lda, int sAn, int sAh,
    const unsigned short* __restrict__ B, int ldb, int sBn, int sBh,
    void* __restrict__ Cv, int ldc, int sC,
    const float* __restrict__ bias, int nK, int Hb, int gx, int gy)
{
  __shared__ unsigned short shA[2][8192];
  __shared__ unsigned short shB[2][8192];

  const int nwg = gridDim.x;
  const int bid = blockIdx.x;
  const int id = (bid & 7) * (nwg >> 3) + (bid >> 3);
  const int pg = gx * gy;
  const int z = id / pg;
  const int rem = id - z * pg;
  const int sc = rem / (gy * 8);
  const int within = rem - sc * (gy * 8);
  const int by = within >> 3;
  const int bx = sc * 8 + (within & 7);

  const int bn = z / Hb, bh = z % Hb;
  const unsigned short* Ab = A + (size_t)bn * sAn + (size_t)bh * sAh;
  const unsigned short* Bb = B + (size_t)bn * sBn + (size_t)bh * sBh;
  const int m0 = by * 128;
  const int n0 = bx * 128;

  const int t = threadIdx.x;
  const int w = t >> 6, l = t & 63;
  const int wr = (w >> 1) * 64, wc = (w & 1) * 64;
  const int lan = l & 15, lgr = l >> 4;

  f32x4 acc[4][4];
#pragma unroll
  for (int m = 0; m < 4; ++m)
#pragma unroll
    for (int n = 0; n < 4; ++n) acc[m][n] = (f32x4){0.f, 0.f, 0.f, 0.f};

  gemm128_2ph(Ab, lda, Bb, ldb, shA, shB, m0, n0, nK, w, l, acc);

  const int zc = z * sC;
#pragma unroll
  for (int m = 0; m < 4; ++m) {
    const int row = m0 + wr + m * 16 + lgr * 4;
#pragma unroll
    for (int n = 0; n < 4; ++n) {
      const int col = n0 + wc + n * 16 + lan;
      const float bcol = (EPI >= 2) ? bias[col] : 0.f;
#pragma unroll
      for (int e = 0; e < 4; ++e) {
        float v = acc[m][n][e];
        const size_t idx = (size_t)zc + (size_t)(row + e) * ldc + col;
        if (EPI == 0) {
          ((float*)Cv)[idx] = v;
        } else if (EPI == 1) {
          ((unsigned short*)Cv)[idx] = f2bf(v);
        } else {
          v += bcol; v = v > 0.f ? v : 0.f;
          ((unsigned short*)Cv)[idx] = f2bf(v);
        }
      }
    }
  }
}

// ---------------------------------------------------------------------------
// Fused projection GEMM: [cat(8192 rows) ; R(256 rows)] @ [Wk|Wv|Wq|Wr]^T
// Plain R7 decode (XCD swizzle cost proj ~5us in R10; fetch latency not
// binding for this kernel).
// ---------------------------------------------------------------------------
__global__ __launch_bounds__(256) void gemm_proj(
    const unsigned short* __restrict__ catA, const unsigned short* __restrict__ wt,
    unsigned short* __restrict__ kb, unsigned short* __restrict__ vb,
    unsigned short* __restrict__ qw, unsigned short* __restrict__ qr,
    unsigned short* __restrict__ rb,
    const float* __restrict__ rwb, const float* __restrict__ rrb)
{
  __shared__ unsigned short shA[2][8192];
  __shared__ unsigned short shB[2][8192];

  const int id = blockIdx.x;
  int by, bx;
  if (id < 1024)      { by = id >> 4;               bx = id & 15; }
  else if (id < 1280) { const int u = id - 1024; by = 32 + (u >> 3); bx = 16 + (u & 7); }
  else                { const int u = id - 1280; by = 64 + (u >> 3); bx = 24 + (u & 7); }
  const int m0 = by * 128, n0 = bx * 128;

  const int t = threadIdx.x;
  const int w = t >> 6, l = t & 63;
  const int wr = (w >> 1) * 64, wc = (w & 1) * 64;
  const int lan = l & 15, lgr = l >> 4;

  f32x4 acc[4][4];
#pragma unroll
  for (int m = 0; m < 4; ++m)
#pragma unroll
    for (int n = 0; n < 4; ++n) acc[m][n] = (f32x4){0.f, 0.f, 0.f, 0.f};

  gemm128_2ph(catA, 1024, wt, 1024, shA, shB, m0, n0, 16, w, l, acc);

#pragma unroll
  for (int m = 0; m < 4; ++m) {
    const int row = m0 + wr + m * 16 + lgr * 4;
#pragma unroll
    for (int n = 0; n < 4; ++n) {
      const int col = n0 + wc + n * 16 + lan;
#pragma unroll
      for (int e = 0; e < 4; ++e) {
        const float v = acc[m][n][e];
        const int r = row + e;
        if (col < 1024) {
          kb[(size_t)r * 1024 + col] = f2bf(v);
        } else if (col < 2048) {
          vb[(size_t)r * 1024 + col - 1024] = f2bf(v);
        } else if (col < 3072) {
          const int c = col - 2048;
          const size_t o = (size_t)(r - 4096) * 1024 + c;
          qw[o] = f2bf(v + rwb[c]);
          qr[o] = f2bf(v + rrb[c]);
        } else {
          const int c = col - 3072;
          rb[(size_t)(r - 8192) * 1024 + c] = f2bf(v);
        }
      }
    }
  }
}

// ---------------------------------------------------------------------------
// Fully fused attention: AC + shifted-BD + masked softmax + PV.
// One block per z=(nn,hh), 4 waves, zero barriers (wave-local LDS).
// ---------------------------------------------------------------------------
__global__ __launch_bounds__(256) void attn_kernel(
    const unsigned short* __restrict__ qw, const unsigned short* __restrict__ qr,
    const unsigned short* __restrict__ kbf, const unsigned short* __restrict__ rbf,
    const int* __restrict__ ep, const unsigned short* __restrict__ V,
    unsigned short* __restrict__ O)
{
  __shared__ unsigned short sS[4][32 * 256];   // 64 KB

  const int z = blockIdx.x;
  const int nn = z >> 4, hh = z & 15;
  const int t = threadIdx.x, w = t >> 6, l = t & 63;
  const int lan = l & 15, lgr = l >> 4;
  const int i0 = w * 32;
  unsigned short* S = sS[w];

  // ---- AC = (q + r_w_bias) . K^T  -> S ----
  bf16x8 av[2][2];
#pragma unroll
  for (int m = 0; m < 2; ++m)
#pragma unroll
    for (int kk = 0; kk < 2; ++kk) {
      const int i = i0 + m * 16 + lan;
      av[m][kk] = *(const bf16x8*)&qw[(size_t)(i * NE + nn) * 1024 + hh * 64 + kk * 32 + lgr * 8];
    }
#pragma unroll
  for (int n = 0; n < 16; ++n) {
    bf16x8 bv[2];
#pragma unroll
    for (int kk = 0; kk < 2; ++kk) {
      const int j = n * 16 + lan;
      bv[kk] = *(const bf16x8*)&kbf[(size_t)(j * NE + nn) * 1024 + hh * 64 + kk * 32 + lgr * 8];
    }
#pragma unroll
    for (int m = 0; m < 2; ++m) {
      f32x4 a4 = (f32x4){0.f, 0.f, 0.f, 0.f};
#pragma unroll
      for (int kk = 0; kk < 2; ++kk)
        a4 = __builtin_amdgcn_mfma_f32_16x16x32_bf16(av[m][kk], bv[kk], a4, 0, 0, 0);
#pragma unroll
      for (int e = 0; e < 4; ++e) {
        const int r = m * 16 + lgr * 4 + e;
        const int j = n * 16 + lan;
        const int swz = ((r >> 2) & 3) * 16;
        S[r * 256 + (j ^ swz)] = f2bf(a4[e]);
      }
    }
  }

  // ---- BD = (q + r_r_bias) . R^T, scatter-add with shift j = j' + i - 127 ----
  bf16x8 bq[2][2];
#pragma unroll
  for (int m = 0; m < 2; ++m)
#pragma unroll
    for (int kk = 0; kk < 2; ++kk) {
      const int i = i0 + m * 16 + lan;
      bq[m][kk] = *(const bf16x8*)&qr[(size_t)(i * NE + nn) * 1024 + hh * 64 + kk * 32 + lgr * 8];
    }
#pragma unroll
  for (int n = 0; n < 16; ++n) {
    bf16x8 bv[2];
#pragma unroll
    for (int kk = 0; kk < 2; ++kk) {
      const int jp = n * 16 + lan;
      bv[kk] = *(const bf16x8*)&rbf[(size_t)jp * 1024 + hh * 64 + kk * 32 + lgr * 8];
    }
#pragma unroll
    for (int m = 0; m < 2; ++m) {
      f32x4 a4 = (f32x4){0.f, 0.f, 0.f, 0.f};
#pragma unroll
      for (int kk = 0; kk < 2; ++kk)
        a4 = __builtin_amdgcn_mfma_f32_16x16x32_bf16(bq[m][kk], bv[kk], a4, 0, 0, 0);
#pragma unroll
      for (int e = 0; e < 4; ++e) {
        const int r = m * 16 + lgr * 4 + e;
        const int i = i0 + r;
        const int jp = n * 16 + lan;
        const int j = jp + i - 127;
        if (j >= 0 && j < 256) {
          const int swz = ((r >> 2) & 3) * 16;
          const int idx = r * 256 + (j ^ swz);
          S[idx] = f2bf(bf2f(S[idx]) + a4[e]);
        }
      }
    }
  }

  // ---- masked softmax, in place ----
  const int j0 = l * 4;
  for (int rr = 0; rr < 32; ++rr) {
    const int i = i0 + rr;
    const int epi = ep[i * NE + nn];
    const int swz = ((rr >> 2) & 3) * 16;
    s16x4 s4 = *(const s16x4*)&S[rr * 256 + (j0 ^ swz)];
    float sc[4];
#pragma unroll
    for (int q = 0; q < 4; ++q) {
      const int j = j0 + q;
      bool allow;
      if (j < M_) {
        allow = (epi == 0);
      } else {
        const int jp = j - M_;
        allow = (jp <= i) && (ep[jp * NE + nn] == epi);
      }
      sc[q] = allow ? bf2f((unsigned short)s4[q]) * 0.125f : -1e9f;
    }
    float mx = fmaxf(fmaxf(sc[0], sc[1]), fmaxf(sc[2], sc[3]));
#pragma unroll
    for (int o = 32; o; o >>= 1) mx = fmaxf(mx, __shfl_xor(mx, o));
    float p[4], sum = 0.f;
#pragma unroll
    for (int q = 0; q < 4; ++q) { p[q] = __expf(sc[q] - mx); sum += p[q]; }
#pragma unroll
    for (int o = 32; o; o >>= 1) sum += __shfl_xor(sum, o);
    const float inv = 1.f / sum;
    s16x4 o4;
#pragma unroll
    for (int q = 0; q < 4; ++q) o4[q] = (short)f2bf(p[q] * inv);
    *(s16x4*)&S[rr * 256 + (j0 ^ swz)] = o4;
  }

  // ---- PV ----
  const unsigned short* Vz = V + hh * DH_;
  f32x4 acc[2][4];
#pragma unroll
  for (int m = 0; m < 2; ++m)
#pragma unroll
    for (int n = 0; n < 4; ++n) acc[m][n] = (f32x4){0.f, 0.f, 0.f, 0.f};

  for (int ks = 0; ks < 8; ++ks) {
    const int kb = ks * 32 + lgr * 8;
    bf16x8 bv2[4];
#pragma unroll
    for (int n = 0; n < 4; ++n) {
      const int d = n * 16 + lan;
      bf16x8 tmp;
#pragma unroll
      for (int jj = 0; jj < 8; ++jj)
        tmp[jj] = (short)Vz[(size_t)((kb + jj) * NE + nn) * 1024 + d];
      bv2[n] = tmp;
    }
    bf16x8 pa[2];
#pragma unroll
    for (int m = 0; m < 2; ++m) {
      const int r = m * 16 + lan;
      const int swz = ((r >> 2) & 3) * 16;
      pa[m] = *(const bf16x8*)&S[r * 256 + (kb ^ swz)];
    }
#pragma unroll
    for (int m = 0; m < 2; ++m)
#pragma unroll
      for (int n = 0; n < 4; ++n)
        acc[m][n] = __builtin_amdgcn_mfma_f32_16x16x32_bf16(pa[m], bv2[n], acc[m][n], 0, 0, 0);
  }
#pragma unroll
  for (int m = 0; m < 2; ++m)
#pragma unroll
    for (int n = 0; n < 4; ++n)
#pragma unroll
      for (int e = 0; e < 4; ++e) {
        const int i = i0 + m * 16 + lgr * 4 + e;
        const int d = n * 16 + lan;
        O[(size_t)(i * NE + nn) * 1024 + hh * DH_ + d] = f2bf(acc[m][n][e]);
      }
}

// ---------------------------------------------------------------------------
// Batched weight transpose: 13 slices of 1024x1024 f32 -> bf16 transposed.
// ---------------------------------------------------------------------------
__global__ __launch_bounds__(256) void transpose13_kernel(
    const float* __restrict__ Wk, const float* __restrict__ Wv,
    const float* __restrict__ Wq, const float* __restrict__ Wr,
    const float* __restrict__ Wo, const float* __restrict__ W1,
    const float* __restrict__ W2,
    unsigned short* __restrict__ wtAll, unsigned short* __restrict__ wto,
    unsigned short* __restrict__ wt1, unsigned short* __restrict__ wt2)
{
  __shared__ float tile[32][33];
  const int zz = blockIdx.z;
  const float* W; unsigned short* WT; int Nd, Kd;
  if (zz < 5) {
    W = (zz == 0) ? Wk : (zz == 1) ? Wv : (zz == 2) ? Wq : (zz == 3) ? Wr : Wo;
    WT = (zz == 4) ? wto : (wtAll + (size_t)zz * 1024 * 1024);
    Nd = 1024; Kd = 1024;
  } else if (zz < 9) {
    const int c = zz - 5;
    W = W1 + (size_t)c * 1024;
    WT = wt1 + (size_t)c * 1024 * 1024;
    Nd = 4096; Kd = 1024;
  } else {
    const int c = zz - 9;
    W = W2 + (size_t)c * 1024 * 1024;
    WT = wt2 + (size_t)c * 1024;
    Nd = 1024; Kd = 4096;
  }
  const int tx = threadIdx.x & 31, ty = threadIdx.x >> 5;
  const int nIn = blockIdx.x * 32 + tx;
  const int kBase = blockIdx.y * 32;
#pragma unroll
  for (int r = 0; r < 32; r += 8)
    tile[ty + r][tx] = W[(size_t)(kBase + ty + r) * Nd + nIn];
  __syncthreads();
#pragma unroll
  for (int r = 0; r < 32; r += 8)
    WT[(size_t)(blockIdx.x * 32 + ty + r) * Kd + kBase + tx] = f2bf(tile[tx][ty + r]);
}

__global__ __launch_bounds__(256) void catmem_kernel(
    const float* __restrict__ mems_l, const float* __restrict__ masks,
    unsigned short* __restrict__ cat)
{
  const int idx = blockIdx.x * 256 + threadIdx.x;
  const int d = idx & 1023;
  const int r = idx >> 10;
  const int nn = r & 31, j = r >> 5;
  const float mk0 = masks[nn];
  cat[idx] = f2bf(mems_l[(size_t)(nn * M_ + j) * 1024 + d] * mk0);
}

__global__ __launch_bounds__(256) void hprep_kernel(
    const float* __restrict__ x, const float* __restrict__ ctx,
    float* __restrict__ h, unsigned short* __restrict__ catUp)
{
  const int idx = blockIdx.x * 256 + threadIdx.x;
  const float v = x[idx] + ctx[idx];
  h[idx] = v;
  catUp[idx] = f2bf(v);
}

__global__ __launch_bounds__(256) void rpos_kernel(unsigned short* __restrict__ R)
{
  const int idx = blockIdx.x * 256 + threadIdx.x;
  const int d = idx & 1023, j = idx >> 10;
  const float pos = (float)(KLEN - 1 - j);
  const int f = d & 511;
  const float inv_freq = __expf(-((float)(2 * f) * (1.f / 1024.f)) * 9.210340371976184f);
  const float ang = pos * inv_freq;
  const float v = (d < 512) ? sinf(ang) : cosf(ang);
  R[idx] = f2bf(v);
}

__global__ void ep_kernel(const float* __restrict__ masks, int* __restrict__ ep)
{
  const int nn = threadIdx.x;
  if (nn < NE) {
    int c = 0;
    for (int i = 0; i < T_; ++i) {
      c += (masks[i * NE + nn] == 0.f) ? 1 : 0;
      ep[i * NE + nn] = c;
    }
  }
}

// y = LN(a + sum_{i<NP} bf16_parts[i] + bias) * g + b
template <int NP>
__global__ __launch_bounds__(256) void ln_kernel(
    const float* __restrict__ a, const unsigned short* __restrict__ parts,
    size_t pstride, const float* __restrict__ bias,
    const float* __restrict__ g, const float* __restrict__ bb,
    float* __restrict__ outf, unsigned short* __restrict__ outbf)
{
  const int row = blockIdx.x;
  const int t = threadIdx.x, w = t >> 6, l = t & 63;
  const int c = t * 4;
  const size_t base = (size_t)row * 1024;
  f32x4 v = *(const f32x4*)&a[base + c];
#pragma unroll
  for (int i = 0; i < NP; ++i) {
    s16x4 pv = *(const s16x4*)&parts[i * pstride + base + c];
#pragma unroll
    for (int q = 0; q < 4; ++q) v[q] += bf2f((unsigned short)pv[q]);
  }
  if (bias) v = v + *(const f32x4*)&bias[c];
  float s = v[0] + v[1] + v[2] + v[3];
#pragma unroll
  for (int o = 32; o; o >>= 1) s += __shfl_xor(s, o);
  __shared__ float red[8];
  if (l == 0) red[w] = s;
  __syncthreads();
  s = red[0] + red[1] + red[2] + red[3];
  const float mu = s * (1.f / 1024.f);
  f32x4 dv = v - mu;
  float s2 = dv[0]*dv[0] + dv[1]*dv[1] + dv[2]*dv[2] + dv[3]*dv[3];
#pragma unroll
  for (int o = 32; o; o >>= 1) s2 += __shfl_xor(s2, o);
  if (l == 0) red[4 + w] = s2;
  __syncthreads();
  s2 = red[4] + red[5] + red[6] + red[7];
  const float inv = rsqrtf(s2 * (1.f / 1024.f) + 1e-5f);
  f32x4 y;
#pragma unroll
  for (int q = 0; q < 4; ++q) y[q] = dv[q] * inv * g[c + q] + bb[c + q];
  *(f32x4*)&outf[base + c] = y;
  if (outbf) {
    s16x4 o4;
#pragma unroll
    for (int q = 0; q < 4; ++q) o4[q] = (short)f2bf(y[q]);
    *(s16x4*)&outbf[base + c] = o4;
  }
}

// ---------------------------------------------------------------------------
extern "C" void kernel_launch(void* const* d_in, const int* in_sizes, int n_in,
                              void* d_out, int out_size, void* d_ws, size_t ws_size,
                              hipStream_t stream)
{
  (void)in_sizes; (void)n_in; (void)out_size; (void)ws_size;
  const float* x    = (const float*)d_in[0];
  const float* ctx  = (const float*)d_in[1];
  const float* mems = (const float*)d_in[2];
  const float* masks= (const float*)d_in[3];
  const float* Wq   = (const float*)d_in[4];
  const float* Wk   = (const float*)d_in[5];
  const float* Wv   = (const float*)d_in[6];
  const float* Wr   = (const float*)d_in[7];
  const float* Wo   = (const float*)d_in[8];
  const float* W1   = (const float*)d_in[9];
  const float* b1   = (const float*)d_in[10];
  const float* W2   = (const float*)d_in[11];
  const float* b2   = (const float*)d_in[12];
  const float* ln1g = (const float*)d_in[13];
  const float* ln1b = (const float*)d_in[14];
  const float* ln2g = (const float*)d_in[15];
  const float* ln2b = (const float*)d_in[16];
  const float* rwb  = (const float*)d_in[17];
  const float* rrb  = (const float*)d_in[18];

  char* ws = (char*)d_ws;
  size_t off = 0;
  auto alloc = [&](size_t bytes) {
    char* p = ws + off;
    off += (bytes + 255) & ~(size_t)255;
    return p;
  };
  unsigned short* wtAll = (unsigned short*)alloc(4096u * 1024 * 2);  // [Wk|Wv|Wq|Wr]^T
  unsigned short* wto = (unsigned short*)alloc(1024u * 1024 * 2);
  unsigned short* wt1 = (unsigned short*)alloc(4096u * 1024 * 2);
  unsigned short* wt2 = (unsigned short*)alloc(4096u * 1024 * 2);
  unsigned short* cat = (unsigned short*)alloc((size_t)(KLEN * NE + 256) * 1024 * 2);
  unsigned short* rbf = (unsigned short*)alloc((size_t)KLEN * 1024 * 2);
  int*            epb = (int*)alloc((size_t)T_ * NE * 4);
  float*          h   = (float*)alloc((size_t)TN * 1024 * 4);
  float*          h1  = (float*)alloc((size_t)TN * 1024 * 4);
  unsigned short* qw  = (unsigned short*)alloc((size_t)TN * 1024 * 2);   // alias: h1_bf
  unsigned short* qr  = (unsigned short*)alloc((size_t)TN * 1024 * 2);
  unsigned short* kbf = (unsigned short*)alloc((size_t)KLEN * NE * 1024 * 2);
  unsigned short* vbf = (unsigned short*)alloc((size_t)KLEN * NE * 1024 * 2);
  unsigned short* ACb = (unsigned short*)alloc((size_t)NB * T_ * KLEN * 2); // alias: f1
  unsigned short* BDb = (unsigned short*)alloc((size_t)NB * T_ * KLEN * 2); // bf16 partials
  unsigned short* obf = (unsigned short*)alloc((size_t)TN * 1024 * 2);

  unsigned short* catUp = cat + (size_t)M_ * NE * 1024;     // h rows (4096..8191)
  unsigned short* catR  = cat + (size_t)KLEN * NE * 1024;   // R rows (8192..8447)
  unsigned short* f1 = ACb;                 // W1 out
  unsigned short* part = BDb;               // 2 bf16 split-K partials (16 MB)
  unsigned short* h1bf = qw;                // qw dead after attn

  rpos_kernel<<<KLEN * 1024 / 256, 256, 0, stream>>>(catR);
  ep_kernel<<<1, 64, 0, stream>>>(masks, epb);
  hprep_kernel<<<TN * 1024 / 256, 256, 0, stream>>>(x, ctx, h, catUp);

  for (int l = 0; l < L_; ++l) {
    const size_t wOff = (size_t)l * 1024 * 1024;
    const size_t wOffBig = (size_t)l * 1024 * 4096;
    transpose13_kernel<<<dim3(32, 32, 13), 256, 0, stream>>>(
        Wk + wOff, Wv + wOff, Wq + wOff, Wr + wOff, Wo + wOff,
        W1 + wOffBig, W2 + wOffBig, wtAll, wto, wt1, wt2);
    catmem_kernel<<<M_ * NE * 1024 / 256, 256, 0, stream>>>(
        mems + (size_t)l * NE * M_ * 1024, masks, cat);

    // fused k|v|q|r projection (1296 blocks, plain decode)
    gemm_proj<<<1296, 256, 0, stream>>>(cat, wtAll, kbf, vbf, qw, qr, rbf, rwb, rrb);

    // fully fused attention (scores + rel_shift + masked softmax + PV)
    attn_kernel<<<NB, 256, 0, stream>>>(qw, qr, kbf, rbf, epb, vbf, obf);

    // output projection, split-K=2 -> bf16 partials; reduce fused into LN1
    gemm_bt<1><<<512, 256, 0, stream>>>(obf, 1024, 0, 512,
                                        wto, 1024, 0, 512,
                                        part, 1024, TN * 1024, nullptr, 8, 2, 8, 32);
    ln_kernel<2><<<TN, 256, 0, stream>>>(h, part, (size_t)TN * 1024, nullptr,
                                         ln1g + l * 1024, ln1b + l * 1024, h1, h1bf);

    // FFN
    gemm_bt<2><<<1024, 256, 0, stream>>>(h1bf, 1024, 0, 0, wt1, 1024, 0, 0,
                                         f1, 4096, 0, b1 + l * 4096, 16, 1, 32, 32);
    gemm_bt<1><<<512, 256, 0, stream>>>(f1, 4096, 0, 2048,
                                        wt2, 4096, 0, 2048,
                                        part, 1024, TN * 1024, nullptr, 32, 2, 8, 32);
    ln_kernel<2><<<TN, 256, 0, stream>>>(h1, part, (size_t)TN * 1024, b2 + l * 1024,
                                         ln2g + l * 1024, ln2b + l * 1024,
                                         (l == L_ - 1) ? (float*)d_out : h, catUp);
  }
}

// Round 12
// 1770.907 us; speedup vs baseline: 1.0996x; 1.0197x over previous
//
#include <hip/hip_runtime.h>
#include <stdint.h>

#define DEV static __device__ __forceinline__

typedef __attribute__((ext_vector_type(4))) float f32x4;
typedef __attribute__((ext_vector_type(8))) short bf16x8;
typedef __attribute__((ext_vector_type(4))) short s16x4;

// dims
static constexpr int L_ = 6, T_ = 128, NE = 32, D_ = 1024, H_ = 16, DH_ = 64, M_ = 128, DI_ = 4096;
static constexpr int KLEN = M_ + T_;   // 256
static constexpr int TN = T_ * NE;     // 4096
static constexpr int NB = NE * H_;     // 512 attention batches

DEV unsigned short f2bf(float f) {
  unsigned u = __builtin_bit_cast(unsigned, f);
  u += 0x7FFFu + ((u >> 16) & 1u);
  return (unsigned short)(u >> 16);
}
DEV float bf2f(unsigned short h) {
  unsigned u = ((unsigned)h) << 16;
  return __builtin_bit_cast(float, u);
}

DEV void gload16(const unsigned short* g, unsigned short* lds) {
  __builtin_amdgcn_global_load_lds(
      (const __attribute__((address_space(1))) unsigned int*)g,
      (__attribute__((address_space(3))) unsigned int*)lds, 16, 0, 0);
}

#define WAITV0 asm volatile("s_waitcnt vmcnt(0)" ::: "memory")

// ---------------------------------------------------------------------------
// 128x128 tile core, BK=64, 4 waves (2x2). T2 XOR-swizzle, 2-phase.
// ---------------------------------------------------------------------------
DEV void stage128(const unsigned short* __restrict__ Ab, int lda,
                  const unsigned short* __restrict__ Bb, int ldb,
                  unsigned short* lA, unsigned short* lB,
                  int m0, int n0, int k0, int w, int l)
{
#pragma unroll
  for (int i = 0; i < 4; ++i) {
    const int obb = i * 4096 + w * 1024;
    const int ob  = obb + (l << 4);
    const int row = ob >> 7;
    const int col = (((ob >> 4) & 7) ^ (row & 7)) << 3;
    gload16(Ab + (size_t)(m0 + row) * lda + k0 + col, lA + (obb >> 1));
    gload16(Bb + (size_t)(n0 + row) * ldb + k0 + col, lB + (obb >> 1));
  }
}

DEV void compute128(const unsigned short* lA, const unsigned short* lB,
                    int w, int l, f32x4 acc[4][4])
{
  const int wr = (w >> 1) * 64, wc = (w & 1) * 64;
  const int lan = l & 15, lgr = l >> 4;
#pragma unroll
  for (int ks = 0; ks < 2; ++ks) {
    bf16x8 av[4], bv[4];
#pragma unroll
    for (int m = 0; m < 4; ++m) {
      const int row = wr + m * 16 + lan;
      const int byte = ((row << 7) + (ks << 6) + (lgr << 4)) ^ ((row & 7) << 4);
      av[m] = *(const bf16x8*)((const char*)lA + byte);
    }
#pragma unroll
    for (int n = 0; n < 4; ++n) {
      const int row = wc + n * 16 + lan;
      const int byte = ((row << 7) + (ks << 6) + (lgr << 4)) ^ ((row & 7) << 4);
      bv[n] = *(const bf16x8*)((const char*)lB + byte);
    }
#pragma unroll
    for (int m = 0; m < 4; ++m)
#pragma unroll
      for (int n = 0; n < 4; ++n)
        acc[m][n] = __builtin_amdgcn_mfma_f32_16x16x32_bf16(av[m], bv[n], acc[m][n], 0, 0, 0);
  }
}

DEV void gemm128_2ph(const unsigned short* __restrict__ Ab, int lda,
                     const unsigned short* __restrict__ Bb, int ldb,
                     unsigned short (*shA)[8192], unsigned short (*shB)[8192],
                     int m0, int n0, int nK, int w, int l, f32x4 acc[4][4])
{
  stage128(Ab, lda, Bb, ldb, shA[0], shB[0], m0, n0, 0, w, l);
  WAITV0;
  __syncthreads();
  int cur = 0;
  for (int kt = 0; kt < nK; ++kt) {
    if (kt + 1 < nK)
      stage128(Ab, lda, Bb, ldb, shA[cur ^ 1], shB[cur ^ 1], m0, n0, (kt + 1) * 64, w, l);
    compute128(shA[cur], shB[cur], w, l, acc);
    WAITV0;
    __syncthreads();
    cur ^= 1;
  }
}

// ---------------------------------------------------------------------------
// Generic batched GEMM, XCD-chunk swizzle + group-of-8 decode (kept for
// W1/W2/o-proj). EPI: 0=f32, 1=bf16, 2=bf16(bias+relu)
// ---------------------------------------------------------------------------
template <int EPI>
__global__ __launch_bounds__(256) void gemm_bt(
    const unsigned short* __restrict__ A, int lda, int sAn, int sAh,
    const unsigned short* __restrict__ B, int ldb, int sBn, int sBh,
    void* __restrict__ Cv, int ldc, int sC,
    const float* __restrict__ bias, int nK, int Hb, int gx, int gy)
{
  __shared__ unsigned short shA[2][8192];
  __shared__ unsigned short shB[2][8192];

  const int nwg = gridDim.x;
  const int bid = blockIdx.x;
  const int id = (bid & 7) * (nwg >> 3) + (bid >> 3);
  const int pg = gx * gy;
  const int z = id / pg;
  const int rem = id - z * pg;
  const int sc = rem / (gy * 8);
  const int within = rem - sc * (gy * 8);
  const int by = within >> 3;
  const int bx = sc * 8 + (within & 7);

  const int bn = z / Hb, bh = z % Hb;
  const unsigned short* Ab = A + (size_t)bn * sAn + (size_t)bh * sAh;
  const unsigned short* Bb = B + (size_t)bn * sBn + (size_t)bh * sBh;
  const int m0 = by * 128;
  const int n0 = bx * 128;

  const int t = threadIdx.x;
  const int w = t >> 6, l = t & 63;
  const int wr = (w >> 1) * 64, wc = (w & 1) * 64;
  const int lan = l & 15, lgr = l >> 4;

  f32x4 acc[4][4];
#pragma unroll
  for (int m = 0; m < 4; ++m)
#pragma unroll
    for (int n = 0; n < 4; ++n) acc[m][n] = (f32x4){0.f, 0.f, 0.f, 0.f};

  gemm128_2ph(Ab, lda, Bb, ldb, shA, shB, m0, n0, nK, w, l, acc);

  const int zc = z * sC;
#pragma unroll
  for (int m = 0; m < 4; ++m) {
    const int row = m0 + wr + m * 16 + lgr * 4;
#pragma unroll
    for (int n = 0; n < 4; ++n) {
      const int col = n0 + wc + n * 16 + lan;
      const float bcol = (EPI >= 2) ? bias[col] : 0.f;
#pragma unroll
      for (int e = 0; e < 4; ++e) {
        float v = acc[m][n][e];
        const size_t idx = (size_t)zc + (size_t)(row + e) * ldc + col;
        if (EPI == 0) {
          ((float*)Cv)[idx] = v;
        } else if (EPI == 1) {
          ((unsigned short*)Cv)[idx] = f2bf(v);
        } else {
          v += bcol; v = v > 0.f ? v : 0.f;
          ((unsigned short*)Cv)[idx] = f2bf(v);
        }
      }
    }
  }
}

// ---------------------------------------------------------------------------
// Fused projection GEMM: [cat(8192 rows) ; R(256 rows)] @ [Wk|Wv|Wq|Wr]^T
// ---------------------------------------------------------------------------
__global__ __launch_bounds__(256) void gemm_proj(
    const unsigned short* __restrict__ catA, const unsigned short* __restrict__ wt,
    unsigned short* __restrict__ kb, unsigned short* __restrict__ vb,
    unsigned short* __restrict__ qw, unsigned short* __restrict__ qr,
    unsigned short* __restrict__ rb,
    const float* __restrict__ rwb, const float* __restrict__ rrb)
{
  __shared__ unsigned short shA[2][8192];
  __shared__ unsigned short shB[2][8192];

  const int id = blockIdx.x;
  int by, bx;
  if (id < 1024)      { by = id >> 4;               bx = id & 15; }
  else if (id < 1280) { const int u = id - 1024; by = 32 + (u >> 3); bx = 16 + (u & 7); }
  else                { const int u = id - 1280; by = 64 + (u >> 3); bx = 24 + (u & 7); }
  const int m0 = by * 128, n0 = bx * 128;

  const int t = threadIdx.x;
  const int w = t >> 6, l = t & 63;
  const int wr = (w >> 1) * 64, wc = (w & 1) * 64;
  const int lan = l & 15, lgr = l >> 4;

  f32x4 acc[4][4];
#pragma unroll
  for (int m = 0; m < 4; ++m)
#pragma unroll
    for (int n = 0; n < 4; ++n) acc[m][n] = (f32x4){0.f, 0.f, 0.f, 0.f};

  gemm128_2ph(catA, 1024, wt, 1024, shA, shB, m0, n0, 16, w, l, acc);

#pragma unroll
  for (int m = 0; m < 4; ++m) {
    const int row = m0 + wr + m * 16 + lgr * 4;
#pragma unroll
    for (int n = 0; n < 4; ++n) {
      const int col = n0 + wc + n * 16 + lan;
#pragma unroll
      for (int e = 0; e < 4; ++e) {
        const float v = acc[m][n][e];
        const int r = row + e;
        if (col < 1024) {
          kb[(size_t)r * 1024 + col] = f2bf(v);
        } else if (col < 2048) {
          vb[(size_t)r * 1024 + col - 1024] = f2bf(v);
        } else if (col < 3072) {
          const int c = col - 2048;
          const size_t o = (size_t)(r - 4096) * 1024 + c;
          qw[o] = f2bf(v + rwb[c]);
          qr[o] = f2bf(v + rrb[c]);
        } else {
          const int c = col - 3072;
          rb[(size_t)(r - 8192) * 1024 + c] = f2bf(v);
        }
      }
    }
  }
}

// ---------------------------------------------------------------------------
// Fully fused attention: AC + shifted-BD + masked softmax + PV.
// One block per z=(nn,hh), 4 waves, zero barriers (wave-local LDS).
// ---------------------------------------------------------------------------
__global__ __launch_bounds__(256) void attn_kernel(
    const unsigned short* __restrict__ qw, const unsigned short* __restrict__ qr,
    const unsigned short* __restrict__ kbf, const unsigned short* __restrict__ rbf,
    const int* __restrict__ ep, const unsigned short* __restrict__ V,
    unsigned short* __restrict__ O)
{
  __shared__ unsigned short sS[4][32 * 256];   // 64 KB

  const int z = blockIdx.x;
  const int nn = z >> 4, hh = z & 15;
  const int t = threadIdx.x, w = t >> 6, l = t & 63;
  const int lan = l & 15, lgr = l >> 4;
  const int i0 = w * 32;
  unsigned short* S = sS[w];

  // ---- AC = (q + r_w_bias) . K^T  -> S ----
  bf16x8 av[2][2];
#pragma unroll
  for (int m = 0; m < 2; ++m)
#pragma unroll
    for (int kk = 0; kk < 2; ++kk) {
      const int i = i0 + m * 16 + lan;
      av[m][kk] = *(const bf16x8*)&qw[(size_t)(i * NE + nn) * 1024 + hh * 64 + kk * 32 + lgr * 8];
    }
#pragma unroll
  for (int n = 0; n < 16; ++n) {
    bf16x8 bv[2];
#pragma unroll
    for (int kk = 0; kk < 2; ++kk) {
      const int j = n * 16 + lan;
      bv[kk] = *(const bf16x8*)&kbf[(size_t)(j * NE + nn) * 1024 + hh * 64 + kk * 32 + lgr * 8];
    }
#pragma unroll
    for (int m = 0; m < 2; ++m) {
      f32x4 a4 = (f32x4){0.f, 0.f, 0.f, 0.f};
#pragma unroll
      for (int kk = 0; kk < 2; ++kk)
        a4 = __builtin_amdgcn_mfma_f32_16x16x32_bf16(av[m][kk], bv[kk], a4, 0, 0, 0);
#pragma unroll
      for (int e = 0; e < 4; ++e) {
        const int r = m * 16 + lgr * 4 + e;
        const int j = n * 16 + lan;
        const int swz = ((r >> 2) & 3) * 16;
        S[r * 256 + (j ^ swz)] = f2bf(a4[e]);
      }
    }
  }

  // ---- BD = (q + r_r_bias) . R^T, scatter-add with shift j = j' + i - 127 ----
  bf16x8 bq[2][2];
#pragma unroll
  for (int m = 0; m < 2; ++m)
#pragma unroll
    for (int kk = 0; kk < 2; ++kk) {
      const int i = i0 + m * 16 + lan;
      bq[m][kk] = *(const bf16x8*)&qr[(size_t)(i * NE + nn) * 1024 + hh * 64 + kk * 32 + lgr * 8];
    }
#pragma unroll
  for (int n = 0; n < 16; ++n) {
    bf16x8 bv[2];
#pragma unroll
    for (int kk = 0; kk < 2; ++kk) {
      const int jp = n * 16 + lan;
      bv[kk] = *(const bf16x8*)&rbf[(size_t)jp * 1024 + hh * 64 + kk * 32 + lgr * 8];
    }
#pragma unroll
    for (int m = 0; m < 2; ++m) {
      f32x4 a4 = (f32x4){0.f, 0.f, 0.f, 0.f};
#pragma unroll
      for (int kk = 0; kk < 2; ++kk)
        a4 = __builtin_amdgcn_mfma_f32_16x16x32_bf16(bq[m][kk], bv[kk], a4, 0, 0, 0);
#pragma unroll
      for (int e = 0; e < 4; ++e) {
        const int r = m * 16 + lgr * 4 + e;
        const int i = i0 + r;
        const int jp = n * 16 + lan;
        const int j = jp + i - 127;
        if (j >= 0 && j < 256) {
          const int swz = ((r >> 2) & 3) * 16;
          const int idx = r * 256 + (j ^ swz);
          S[idx] = f2bf(bf2f(S[idx]) + a4[e]);
        }
      }
    }
  }

  // ---- masked softmax, in place ----
  const int j0 = l * 4;
  for (int rr = 0; rr < 32; ++rr) {
    const int i = i0 + rr;
    const int epi = ep[i * NE + nn];
    const int swz = ((rr >> 2) & 3) * 16;
    s16x4 s4 = *(const s16x4*)&S[rr * 256 + (j0 ^ swz)];
    float sc[4];
#pragma unroll
    for (int q = 0; q < 4; ++q) {
      const int j = j0 + q;
      bool allow;
      if (j < M_) {
        allow = (epi == 0);
      } else {
        const int jp = j - M_;
        allow = (jp <= i) && (ep[jp * NE + nn] == epi);
      }
      sc[q] = allow ? bf2f((unsigned short)s4[q]) * 0.125f : -1e9f;
    }
    float mx = fmaxf(fmaxf(sc[0], sc[1]), fmaxf(sc[2], sc[3]));
#pragma unroll
    for (int o = 32; o; o >>= 1) mx = fmaxf(mx, __shfl_xor(mx, o));
    float p[4], sum = 0.f;
#pragma unroll
    for (int q = 0; q < 4; ++q) { p[q] = __expf(sc[q] - mx); sum += p[q]; }
#pragma unroll
    for (int o = 32; o; o >>= 1) sum += __shfl_xor(sum, o);
    const float inv = 1.f / sum;
    s16x4 o4;
#pragma unroll
    for (int q = 0; q < 4; ++q) o4[q] = (short)f2bf(p[q] * inv);
    *(s16x4*)&S[rr * 256 + (j0 ^ swz)] = o4;
  }

  // ---- PV ----
  const unsigned short* Vz = V + hh * DH_;
  f32x4 acc[2][4];
#pragma unroll
  for (int m = 0; m < 2; ++m)
#pragma unroll
    for (int n = 0; n < 4; ++n) acc[m][n] = (f32x4){0.f, 0.f, 0.f, 0.f};

  for (int ks = 0; ks < 8; ++ks) {
    const int kb = ks * 32 + lgr * 8;
    bf16x8 bv2[4];
#pragma unroll
    for (int n = 0; n < 4; ++n) {
      const int d = n * 16 + lan;
      bf16x8 tmp;
#pragma unroll
      for (int jj = 0; jj < 8; ++jj)
        tmp[jj] = (short)Vz[(size_t)((kb + jj) * NE + nn) * 1024 + d];
      bv2[n] = tmp;
    }
    bf16x8 pa[2];
#pragma unroll
    for (int m = 0; m < 2; ++m) {
      const int r = m * 16 + lan;
      const int swz = ((r >> 2) & 3) * 16;
      pa[m] = *(const bf16x8*)&S[r * 256 + (kb ^ swz)];
    }
#pragma unroll
    for (int m = 0; m < 2; ++m)
#pragma unroll
      for (int n = 0; n < 4; ++n)
        acc[m][n] = __builtin_amdgcn_mfma_f32_16x16x32_bf16(pa[m], bv2[n], acc[m][n], 0, 0, 0);
  }
#pragma unroll
  for (int m = 0; m < 2; ++m)
#pragma unroll
    for (int n = 0; n < 4; ++n)
#pragma unroll
      for (int e = 0; e < 4; ++e) {
        const int i = i0 + m * 16 + lgr * 4 + e;
        const int d = n * 16 + lan;
        O[(size_t)(i * NE + nn) * 1024 + hh * DH_ + d] = f2bf(acc[m][n][e]);
      }
}

// ---------------------------------------------------------------------------
// Batched weight transpose: 13 slices of 1024x1024 f32 -> bf16 transposed.
// ---------------------------------------------------------------------------
__global__ __launch_bounds__(256) void transpose13_kernel(
    const float* __restrict__ Wk, const float* __restrict__ Wv,
    const float* __restrict__ Wq, const float* __restrict__ Wr,
    const float* __restrict__ Wo, const float* __restrict__ W1,
    const float* __restrict__ W2,
    unsigned short* __restrict__ wtAll, unsigned short* __restrict__ wto,
    unsigned short* __restrict__ wt1, unsigned short* __restrict__ wt2)
{
  __shared__ float tile[32][33];
  const int zz = blockIdx.z;
  const float* W; unsigned short* WT; int Nd, Kd;
  if (zz < 5) {
    W = (zz == 0) ? Wk : (zz == 1) ? Wv : (zz == 2) ? Wq : (zz == 3) ? Wr : Wo;
    WT = (zz == 4) ? wto : (wtAll + (size_t)zz * 1024 * 1024);
    Nd = 1024; Kd = 1024;
  } else if (zz < 9) {
    const int c = zz - 5;
    W = W1 + (size_t)c * 1024;
    WT = wt1 + (size_t)c * 1024 * 1024;
    Nd = 4096; Kd = 1024;
  } else {
    const int c = zz - 9;
    W = W2 + (size_t)c * 1024 * 1024;
    WT = wt2 + (size_t)c * 1024;
    Nd = 1024; Kd = 4096;
  }
  const int tx = threadIdx.x & 31, ty = threadIdx.x >> 5;
  const int nIn = blockIdx.x * 32 + tx;
  const int kBase = blockIdx.y * 32;
#pragma unroll
  for (int r = 0; r < 32; r += 8)
    tile[ty + r][tx] = W[(size_t)(kBase + ty + r) * Nd + nIn];
  __syncthreads();
#pragma unroll
  for (int r = 0; r < 32; r += 8)
    WT[(size_t)(blockIdx.x * 32 + ty + r) * Kd + kBase + tx] = f2bf(tile[tx][ty + r]);
}

__global__ __launch_bounds__(256) void catmem_kernel(
    const float* __restrict__ mems_l, const float* __restrict__ masks,
    unsigned short* __restrict__ cat)
{
  const int idx = blockIdx.x * 256 + threadIdx.x;
  const int d = idx & 1023;
  const int r = idx >> 10;
  const int nn = r & 31, j = r >> 5;
  const float mk0 = masks[nn];
  cat[idx] = f2bf(mems_l[(size_t)(nn * M_ + j) * 1024 + d] * mk0);
}

// h = bf16(x + ctx) -> catUp (single residual copy)
__global__ __launch_bounds__(256) void hprep_kernel(
    const float* __restrict__ x, const float* __restrict__ ctx,
    unsigned short* __restrict__ catUp)
{
  const int idx = blockIdx.x * 256 + threadIdx.x;
  catUp[idx] = f2bf(x[idx] + ctx[idx]);
}

__global__ __launch_bounds__(256) void rpos_kernel(unsigned short* __restrict__ R)
{
  const int idx = blockIdx.x * 256 + threadIdx.x;
  const int d = idx & 1023, j = idx >> 10;
  const float pos = (float)(KLEN - 1 - j);
  const int f = d & 511;
  const float inv_freq = __expf(-((float)(2 * f) * (1.f / 1024.f)) * 9.210340371976184f);
  const float ang = pos * inv_freq;
  const float v = (d < 512) ? sinf(ang) : cosf(ang);
  R[idx] = f2bf(v);
}

__global__ void ep_kernel(const float* __restrict__ masks, int* __restrict__ ep)
{
  const int nn = threadIdx.x;
  if (nn < NE) {
    int c = 0;
    for (int i = 0; i < T_; ++i) {
      c += (masks[i * NE + nn] == 0.f) ? 1 : 0;
      ep[i * NE + nn] = c;
    }
  }
}

// y = LN(bf16_a + sum bf16_parts + bias) * g + b ; writes bf16 out (+f32 opt)
template <int NP, bool WRITEF>
__global__ __launch_bounds__(256) void ln_kernel(
    const unsigned short* __restrict__ a, const unsigned short* __restrict__ parts,
    size_t pstride, const float* __restrict__ bias,
    const float* __restrict__ g, const float* __restrict__ bb,
    unsigned short* __restrict__ outbf, float* __restrict__ outf)
{
  const int row = blockIdx.x;
  const int t = threadIdx.x, w = t >> 6, l = t & 63;
  const int c = t * 4;
  const size_t base = (size_t)row * 1024;
  s16x4 av = *(const s16x4*)&a[base + c];
  f32x4 v;
#pragma unroll
  for (int q = 0; q < 4; ++q) v[q] = bf2f((unsigned short)av[q]);
#pragma unroll
  for (int i = 0; i < NP; ++i) {
    s16x4 pv = *(const s16x4*)&parts[i * pstride + base + c];
#pragma unroll
    for (int q = 0; q < 4; ++q) v[q] += bf2f((unsigned short)pv[q]);
  }
  if (bias) v = v + *(const f32x4*)&bias[c];
  float s = v[0] + v[1] + v[2] + v[3];
#pragma unroll
  for (int o = 32; o; o >>= 1) s += __shfl_xor(s, o);
  __shared__ float red[8];
  if (l == 0) red[w] = s;
  __syncthreads();
  s = red[0] + red[1] + red[2] + red[3];
  const float mu = s * (1.f / 1024.f);
  f32x4 dv = v - mu;
  float s2 = dv[0]*dv[0] + dv[1]*dv[1] + dv[2]*dv[2] + dv[3]*dv[3];
#pragma unroll
  for (int o = 32; o; o >>= 1) s2 += __shfl_xor(s2, o);
  if (l == 0) red[4 + w] = s2;
  __syncthreads();
  s2 = red[4] + red[5] + red[6] + red[7];
  const float inv = rsqrtf(s2 * (1.f / 1024.f) + 1e-5f);
  f32x4 y;
#pragma unroll
  for (int q = 0; q < 4; ++q) y[q] = dv[q] * inv * g[c + q] + bb[c + q];
  s16x4 o4;
#pragma unroll
  for (int q = 0; q < 4; ++q) o4[q] = (short)f2bf(y[q]);
  *(s16x4*)&outbf[base + c] = o4;
  if (WRITEF) *(f32x4*)&outf[base + c] = y;
}

// ---------------------------------------------------------------------------
extern "C" void kernel_launch(void* const* d_in, const int* in_sizes, int n_in,
                              void* d_out, int out_size, void* d_ws, size_t ws_size,
                              hipStream_t stream)
{
  (void)in_sizes; (void)n_in; (void)out_size; (void)ws_size;
  const float* x    = (const float*)d_in[0];
  const float* ctx  = (const float*)d_in[1];
  const float* mems = (const float*)d_in[2];
  const float* masks= (const float*)d_in[3];
  const float* Wq   = (const float*)d_in[4];
  const float* Wk   = (const float*)d_in[5];
  const float* Wv   = (const float*)d_in[6];
  const float* Wr   = (const float*)d_in[7];
  const float* Wo   = (const float*)d_in[8];
  const float* W1   = (const float*)d_in[9];
  const float* b1   = (const float*)d_in[10];
  const float* W2   = (const float*)d_in[11];
  const float* b2   = (const float*)d_in[12];
  const float* ln1g = (const float*)d_in[13];
  const float* ln1b = (const float*)d_in[14];
  const float* ln2g = (const float*)d_in[15];
  const float* ln2b = (const float*)d_in[16];
  const float* rwb  = (const float*)d_in[17];
  const float* rrb  = (const float*)d_in[18];

  char* ws = (char*)d_ws;
  size_t off = 0;
  auto alloc = [&](size_t bytes) {
    char* p = ws + off;
    off += (bytes + 255) & ~(size_t)255;
    return p;
  };
  unsigned short* wtAll = (unsigned short*)alloc(4096u * 1024 * 2);  // [Wk|Wv|Wq|Wr]^T
  unsigned short* wto = (unsigned short*)alloc(1024u * 1024 * 2);
  unsigned short* wt1 = (unsigned short*)alloc(4096u * 1024 * 2);
  unsigned short* wt2 = (unsigned short*)alloc(4096u * 1024 * 2);
  unsigned short* cat = (unsigned short*)alloc((size_t)(KLEN * NE + 256) * 1024 * 2);
  unsigned short* rbf = (unsigned short*)alloc((size_t)KLEN * 1024 * 2);
  int*            epb = (int*)alloc((size_t)T_ * NE * 4);
  unsigned short* h1bf= (unsigned short*)alloc((size_t)TN * 1024 * 2);   // LN1 out
  unsigned short* qw  = (unsigned short*)alloc((size_t)TN * 1024 * 2);
  unsigned short* qr  = (unsigned short*)alloc((size_t)TN * 1024 * 2);
  unsigned short* kbf = (unsigned short*)alloc((size_t)KLEN * NE * 1024 * 2);
  unsigned short* vbf = (unsigned short*)alloc((size_t)KLEN * NE * 1024 * 2);
  unsigned short* ACb = (unsigned short*)alloc((size_t)NB * T_ * KLEN * 2); // alias: f1
  unsigned short* BDb = (unsigned short*)alloc((size_t)NB * T_ * KLEN * 2); // bf16 partials
  unsigned short* obf = (unsigned short*)alloc((size_t)TN * 1024 * 2);

  unsigned short* catUp = cat + (size_t)M_ * NE * 1024;     // residual stream (bf16)
  unsigned short* catR  = cat + (size_t)KLEN * NE * 1024;   // R rows (8192..8447)
  unsigned short* f1 = ACb;                 // W1 out
  unsigned short* part = BDb;               // 2 bf16 split-K partials (16 MB)

  rpos_kernel<<<KLEN * 1024 / 256, 256, 0, stream>>>(catR);
  ep_kernel<<<1, 64, 0, stream>>>(masks, epb);
  hprep_kernel<<<TN * 1024 / 256, 256, 0, stream>>>(x, ctx, catUp);

  for (int l = 0; l < L_; ++l) {
    const size_t wOff = (size_t)l * 1024 * 1024;
    const size_t wOffBig = (size_t)l * 1024 * 4096;
    transpose13_kernel<<<dim3(32, 32, 13), 256, 0, stream>>>(
        Wk + wOff, Wv + wOff, Wq + wOff, Wr + wOff, Wo + wOff,
        W1 + wOffBig, W2 + wOffBig, wtAll, wto, wt1, wt2);
    catmem_kernel<<<M_ * NE * 1024 / 256, 256, 0, stream>>>(
        mems + (size_t)l * NE * M_ * 1024, masks, cat);

    // fused k|v|q|r projection (1296 blocks, plain decode)
    gemm_proj<<<1296, 256, 0, stream>>>(cat, wtAll, kbf, vbf, qw, qr, rbf, rwb, rrb);

    // fully fused attention (scores + rel_shift + masked softmax + PV)
    attn_kernel<<<NB, 256, 0, stream>>>(qw, qr, kbf, rbf, epb, vbf, obf);

    // output projection, split-K=2 -> bf16 partials; reduce fused into LN1
    gemm_bt<1><<<512, 256, 0, stream>>>(obf, 1024, 0, 512,
                                        wto, 1024, 0, 512,
                                        part, 1024, TN * 1024, nullptr, 8, 2, 8, 32);
    // LN1: residual = catUp (bf16), out -> h1bf
    ln_kernel<2, false><<<TN, 256, 0, stream>>>(catUp, part, (size_t)TN * 1024, nullptr,
                                                ln1g + l * 1024, ln1b + l * 1024,
                                                h1bf, nullptr);

    // FFN
    gemm_bt<2><<<1024, 256, 0, stream>>>(h1bf, 1024, 0, 0, wt1, 1024, 0, 0,
                                         f1, 4096, 0, b1 + l * 4096, 16, 1, 32, 32);
    gemm_bt<1><<<512, 256, 0, stream>>>(f1, 4096, 0, 2048,
                                        wt2, 4096, 0, 2048,
                                        part, 1024, TN * 1024, nullptr, 32, 2, 8, 32);
    // LN2: residual = h1bf, out -> catUp (next layer); f32 d_out on last layer
    if (l == L_ - 1) {
      ln_kernel<2, true><<<TN, 256, 0, stream>>>(h1bf, part, (size_t)TN * 1024,
                                                 b2 + l * 1024, ln2g + l * 1024,
                                                 ln2b + l * 1024, catUp, (float*)d_out);
    } else {
      ln_kernel<2, false><<<TN, 256, 0, stream>>>(h1bf, part, (size_t)TN * 1024,
                                                  b2 + l * 1024, ln2g + l * 1024,
                                                  ln2b + l * 1024, catUp, nullptr);
    }
  }
}

// Round 13
// 1744.062 us; speedup vs baseline: 1.1165x; 1.0154x over previous
//
#include <hip/hip_runtime.h>
#include <stdint.h>

#define DEV static __device__ __forceinline__

typedef __attribute__((ext_vector_type(4))) float f32x4;
typedef __attribute__((ext_vector_type(8))) short bf16x8;
typedef __attribute__((ext_vector_type(4))) short s16x4;

// dims
static constexpr int L_ = 6, T_ = 128, NE = 32, D_ = 1024, H_ = 16, DH_ = 64, M_ = 128, DI_ = 4096;
static constexpr int KLEN = M_ + T_;   // 256
static constexpr int TN = T_ * NE;     // 4096
static constexpr int NB = NE * H_;     // 512 attention batches

DEV unsigned short f2bf(float f) {
  unsigned u = __builtin_bit_cast(unsigned, f);
  u += 0x7FFFu + ((u >> 16) & 1u);
  return (unsigned short)(u >> 16);
}
DEV float bf2f(unsigned short h) {
  unsigned u = ((unsigned)h) << 16;
  return __builtin_bit_cast(float, u);
}

DEV void gload16(const unsigned short* g, unsigned short* lds) {
  __builtin_amdgcn_global_load_lds(
      (const __attribute__((address_space(1))) unsigned int*)g,
      (__attribute__((address_space(3))) unsigned int*)lds, 16, 0, 0);
}

#define WAITV0 asm volatile("s_waitcnt vmcnt(0)" ::: "memory")

// ---------------------------------------------------------------------------
// 128x128 tile core, BK=64, 4 waves (2x2). T2 XOR-swizzle, 2-phase.
// ---------------------------------------------------------------------------
DEV void stage128(const unsigned short* __restrict__ Ab, int lda,
                  const unsigned short* __restrict__ Bb, int ldb,
                  unsigned short* lA, unsigned short* lB,
                  int m0, int n0, int k0, int w, int l)
{
#pragma unroll
  for (int i = 0; i < 4; ++i) {
    const int obb = i * 4096 + w * 1024;
    const int ob  = obb + (l << 4);
    const int row = ob >> 7;
    const int col = (((ob >> 4) & 7) ^ (row & 7)) << 3;
    gload16(Ab + (size_t)(m0 + row) * lda + k0 + col, lA + (obb >> 1));
    gload16(Bb + (size_t)(n0 + row) * ldb + k0 + col, lB + (obb >> 1));
  }
}

DEV void compute128(const unsigned short* lA, const unsigned short* lB,
                    int w, int l, f32x4 acc[4][4])
{
  const int wr = (w >> 1) * 64, wc = (w & 1) * 64;
  const int lan = l & 15, lgr = l >> 4;
#pragma unroll
  for (int ks = 0; ks < 2; ++ks) {
    bf16x8 av[4], bv[4];
#pragma unroll
    for (int m = 0; m < 4; ++m) {
      const int row = wr + m * 16 + lan;
      const int byte = ((row << 7) + (ks << 6) + (lgr << 4)) ^ ((row & 7) << 4);
      av[m] = *(const bf16x8*)((const char*)lA + byte);
    }
#pragma unroll
    for (int n = 0; n < 4; ++n) {
      const int row = wc + n * 16 + lan;
      const int byte = ((row << 7) + (ks << 6) + (lgr << 4)) ^ ((row & 7) << 4);
      bv[n] = *(const bf16x8*)((const char*)lB + byte);
    }
#pragma unroll
    for (int m = 0; m < 4; ++m)
#pragma unroll
      for (int n = 0; n < 4; ++n)
        acc[m][n] = __builtin_amdgcn_mfma_f32_16x16x32_bf16(av[m], bv[n], acc[m][n], 0, 0, 0);
  }
}

DEV void gemm128_2ph(const unsigned short* __restrict__ Ab, int lda,
                     const unsigned short* __restrict__ Bb, int ldb,
                     unsigned short (*shA)[8192], unsigned short (*shB)[8192],
                     int m0, int n0, int nK, int w, int l, f32x4 acc[4][4])
{
  stage128(Ab, lda, Bb, ldb, shA[0], shB[0], m0, n0, 0, w, l);
  WAITV0;
  __syncthreads();
  int cur = 0;
  for (int kt = 0; kt < nK; ++kt) {
    if (kt + 1 < nK)
      stage128(Ab, lda, Bb, ldb, shA[cur ^ 1], shB[cur ^ 1], m0, n0, (kt + 1) * 64, w, l);
    compute128(shA[cur], shB[cur], w, l, acc);
    WAITV0;
    __syncthreads();
    cur ^= 1;
  }
}

// ---------------------------------------------------------------------------
// 256x256 tile core, BK=64, 8 waves (2M x 4N), SAME 2-phase schedule and
// swizzle as 128^2. LDS 128 KB double-buffered, 1 blk/CU. Used for W1 only
// (full K, 256-block grid = exactly 1 round, zero tail).
// ---------------------------------------------------------------------------
DEV void stage256(const unsigned short* __restrict__ Ab, int lda,
                  const unsigned short* __restrict__ Bb, int ldb,
                  unsigned short* lA, unsigned short* lB,
                  int m0, int n0, int k0, int t)
{
#pragma unroll
  for (int i = 0; i < 4; ++i) {
    const int obb = i * 8192 + (t >> 6) * 1024;
    const int ob  = obb + ((t & 63) << 4);
    const int row = ob >> 7;
    const int col = (((ob >> 4) & 7) ^ (row & 7)) << 3;
    gload16(Ab + (size_t)(m0 + row) * lda + k0 + col, lA + (obb >> 1));
    gload16(Bb + (size_t)(n0 + row) * ldb + k0 + col, lB + (obb >> 1));
  }
}

DEV void compute256(const unsigned short* lA, const unsigned short* lB,
                    int w, int l, f32x4 acc[8][4])
{
  const int wm = w >> 2, wn = w & 3;
  const int lan = l & 15, lgr = l >> 4;
#pragma unroll
  for (int ks = 0; ks < 2; ++ks) {
    bf16x8 av[8], bv[4];
#pragma unroll
    for (int m = 0; m < 8; ++m) {
      const int row = wm * 128 + m * 16 + lan;
      const int byte = ((row << 7) + (ks << 6) + (lgr << 4)) ^ ((row & 7) << 4);
      av[m] = *(const bf16x8*)((const char*)lA + byte);
    }
#pragma unroll
    for (int n = 0; n < 4; ++n) {
      const int row = wn * 64 + n * 16 + lan;
      const int byte = ((row << 7) + (ks << 6) + (lgr << 4)) ^ ((row & 7) << 4);
      bv[n] = *(const bf16x8*)((const char*)lB + byte);
    }
#pragma unroll
    for (int m = 0; m < 8; ++m)
#pragma unroll
      for (int n = 0; n < 4; ++n)
        acc[m][n] = __builtin_amdgcn_mfma_f32_16x16x32_bf16(av[m], bv[n], acc[m][n], 0, 0, 0);
  }
}

// W1 GEMM on 256^2 tiles: C = relu(A @ Bt + bias), bf16 out.
__global__ __launch_bounds__(512) void gemm256_w1(
    const unsigned short* __restrict__ A, const unsigned short* __restrict__ B,
    unsigned short* __restrict__ C, const float* __restrict__ bias)
{
  __shared__ unsigned short shA[2][16384];
  __shared__ unsigned short shB[2][16384];
  const int m0 = blockIdx.y * 256, n0 = blockIdx.x * 256;
  const int t = threadIdx.x;
  const int w = t >> 6, l = t & 63;

  f32x4 acc[8][4];
#pragma unroll
  for (int m = 0; m < 8; ++m)
#pragma unroll
    for (int n = 0; n < 4; ++n) acc[m][n] = (f32x4){0.f, 0.f, 0.f, 0.f};

  stage256(A, 1024, B, 1024, shA[0], shB[0], m0, n0, 0, t);
  WAITV0;
  __syncthreads();
  int cur = 0;
  for (int kt = 0; kt < 16; ++kt) {
    if (kt + 1 < 16)
      stage256(A, 1024, B, 1024, shA[cur ^ 1], shB[cur ^ 1], m0, n0, (kt + 1) * 64, t);
    compute256(shA[cur], shB[cur], w, l, acc);
    WAITV0;
    __syncthreads();
    cur ^= 1;
  }

  const int wm = w >> 2, wn = w & 3, lan = l & 15, lgr = l >> 4;
#pragma unroll
  for (int m = 0; m < 8; ++m) {
    const int row = m0 + wm * 128 + m * 16 + lgr * 4;
#pragma unroll
    for (int n = 0; n < 4; ++n) {
      const int col = n0 + wn * 64 + n * 16 + lan;
      const float bcol = bias[col];
#pragma unroll
      for (int e = 0; e < 4; ++e) {
        float v = acc[m][n][e] + bcol;
        v = v > 0.f ? v : 0.f;
        C[(size_t)(row + e) * 4096 + col] = f2bf(v);
      }
    }
  }
}

// ---------------------------------------------------------------------------
// Generic batched GEMM (128^2), XCD-chunk swizzle + group-of-8 decode.
// EPI: 0=f32, 1=bf16, 2=bf16(bias+relu)
// ---------------------------------------------------------------------------
template <int EPI>
__global__ __launch_bounds__(256) void gemm_bt(
    const unsigned short* __restrict__ A, int lda, int sAn, int sAh,
    const unsigned short* __restrict__ B, int ldb, int sBn, int sBh,
    void* __restrict__ Cv, int ldc, int sC,
    const float* __restrict__ bias, int nK, int Hb, int gx, int gy)
{
  __shared__ unsigned short shA[2][8192];
  __shared__ unsigned short shB[2][8192];

  const int nwg = gridDim.x;
  const int bid = blockIdx.x;
  const int id = (bid & 7) * (nwg >> 3) + (bid >> 3);
  const int pg = gx * gy;
  const int z = id / pg;
  const int rem = id - z * pg;
  const int sc = rem / (gy * 8);
  const int within = rem - sc * (gy * 8);
  const int by = within >> 3;
  const int bx = sc * 8 + (within & 7);

  const int bn = z / Hb, bh = z % Hb;
  const unsigned short* Ab = A + (size_t)bn * sAn + (size_t)bh * sAh;
  const unsigned short* Bb = B + (size_t)bn * sBn + (size_t)bh * sBh;
  const int m0 = by * 128;
  const int n0 = bx * 128;

  const int t = threadIdx.x;
  const int w = t >> 6, l = t & 63;
  const int wr = (w >> 1) * 64, wc = (w & 1) * 64;
  const int lan = l & 15, lgr = l >> 4;

  f32x4 acc[4][4];
#pragma unroll
  for (int m = 0; m < 4; ++m)
#pragma unroll
    for (int n = 0; n < 4; ++n) acc[m][n] = (f32x4){0.f, 0.f, 0.f, 0.f};

  gemm128_2ph(Ab, lda, Bb, ldb, shA, shB, m0, n0, nK, w, l, acc);

  const int zc = z * sC;
#pragma unroll
  for (int m = 0; m < 4; ++m) {
    const int row = m0 + wr + m * 16 + lgr * 4;
#pragma unroll
    for (int n = 0; n < 4; ++n) {
      const int col = n0 + wc + n * 16 + lan;
      const float bcol = (EPI >= 2) ? bias[col] : 0.f;
#pragma unroll
      for (int e = 0; e < 4; ++e) {
        float v = acc[m][n][e];
        const size_t idx = (size_t)zc + (size_t)(row + e) * ldc + col;
        if (EPI == 0) {
          ((float*)Cv)[idx] = v;
        } else if (EPI == 1) {
          ((unsigned short*)Cv)[idx] = f2bf(v);
        } else {
          v += bcol; v = v > 0.f ? v : 0.f;
          ((unsigned short*)Cv)[idx] = f2bf(v);
        }
      }
    }
  }
}

// ---------------------------------------------------------------------------
// Fused projection GEMM: [cat(8192 rows) ; R(256 rows)] @ [Wk|Wv|Wq|Wr]^T
// ---------------------------------------------------------------------------
__global__ __launch_bounds__(256) void gemm_proj(
    const unsigned short* __restrict__ catA, const unsigned short* __restrict__ wt,
    unsigned short* __restrict__ kb, unsigned short* __restrict__ vb,
    unsigned short* __restrict__ qw, unsigned short* __restrict__ qr,
    unsigned short* __restrict__ rb,
    const float* __restrict__ rwb, const float* __restrict__ rrb)
{
  __shared__ unsigned short shA[2][8192];
  __shared__ unsigned short shB[2][8192];

  const int id = blockIdx.x;
  int by, bx;
  if (id < 1024)      { by = id >> 4;               bx = id & 15; }
  else if (id < 1280) { const int u = id - 1024; by = 32 + (u >> 3); bx = 16 + (u & 7); }
  else                { const int u = id - 1280; by = 64 + (u >> 3); bx = 24 + (u & 7); }
  const int m0 = by * 128, n0 = bx * 128;

  const int t = threadIdx.x;
  const int w = t >> 6, l = t & 63;
  const int wr = (w >> 1) * 64, wc = (w & 1) * 64;
  const int lan = l & 15, lgr = l >> 4;

  f32x4 acc[4][4];
#pragma unroll
  for (int m = 0; m < 4; ++m)
#pragma unroll
    for (int n = 0; n < 4; ++n) acc[m][n] = (f32x4){0.f, 0.f, 0.f, 0.f};

  gemm128_2ph(catA, 1024, wt, 1024, shA, shB, m0, n0, 16, w, l, acc);

#pragma unroll
  for (int m = 0; m < 4; ++m) {
    const int row = m0 + wr + m * 16 + lgr * 4;
#pragma unroll
    for (int n = 0; n < 4; ++n) {
      const int col = n0 + wc + n * 16 + lan;
#pragma unroll
      for (int e = 0; e < 4; ++e) {
        const float v = acc[m][n][e];
        const int r = row + e;
        if (col < 1024) {
          kb[(size_t)r * 1024 + col] = f2bf(v);
        } else if (col < 2048) {
          vb[(size_t)r * 1024 + col - 1024] = f2bf(v);
        } else if (col < 3072) {
          const int c = col - 2048;
          const size_t o = (size_t)(r - 4096) * 1024 + c;
          qw[o] = f2bf(v + rwb[c]);
          qr[o] = f2bf(v + rrb[c]);
        } else {
          const int c = col - 3072;
          rb[(size_t)(r - 8192) * 1024 + c] = f2bf(v);
        }
      }
    }
  }
}

// ---------------------------------------------------------------------------
// Fully fused attention: AC + shifted-BD + masked softmax + PV.
// ---------------------------------------------------------------------------
__global__ __launch_bounds__(256) void attn_kernel(
    const unsigned short* __restrict__ qw, const unsigned short* __restrict__ qr,
    const unsigned short* __restrict__ kbf, const unsigned short* __restrict__ rbf,
    const int* __restrict__ ep, const unsigned short* __restrict__ V,
    unsigned short* __restrict__ O)
{
  __shared__ unsigned short sS[4][32 * 256];   // 64 KB

  const int z = blockIdx.x;
  const int nn = z >> 4, hh = z & 15;
  const int t = threadIdx.x, w = t >> 6, l = t & 63;
  const int lan = l & 15, lgr = l >> 4;
  const int i0 = w * 32;
  unsigned short* S = sS[w];

  // ---- AC = (q + r_w_bias) . K^T  -> S ----
  bf16x8 av[2][2];
#pragma unroll
  for (int m = 0; m < 2; ++m)
#pragma unroll
    for (int kk = 0; kk < 2; ++kk) {
      const int i = i0 + m * 16 + lan;
      av[m][kk] = *(const bf16x8*)&qw[(size_t)(i * NE + nn) * 1024 + hh * 64 + kk * 32 + lgr * 8];
    }
#pragma unroll
  for (int n = 0; n < 16; ++n) {
    bf16x8 bv[2];
#pragma unroll
    for (int kk = 0; kk < 2; ++kk) {
      const int j = n * 16 + lan;
      bv[kk] = *(const bf16x8*)&kbf[(size_t)(j * NE + nn) * 1024 + hh * 64 + kk * 32 + lgr * 8];
    }
#pragma unroll
    for (int m = 0; m < 2; ++m) {
      f32x4 a4 = (f32x4){0.f, 0.f, 0.f, 0.f};
#pragma unroll
      for (int kk = 0; kk < 2; ++kk)
        a4 = __builtin_amdgcn_mfma_f32_16x16x32_bf16(av[m][kk], bv[kk], a4, 0, 0, 0);
#pragma unroll
      for (int e = 0; e < 4; ++e) {
        const int r = m * 16 + lgr * 4 + e;
        const int j = n * 16 + lan;
        const int swz = ((r >> 2) & 3) * 16;
        S[r * 256 + (j ^ swz)] = f2bf(a4[e]);
      }
    }
  }

  // ---- BD = (q + r_r_bias) . R^T, scatter-add with shift j = j' + i - 127 ----
  bf16x8 bq[2][2];
#pragma unroll
  for (int m = 0; m < 2; ++m)
#pragma unroll
    for (int kk = 0; kk < 2; ++kk) {
      const int i = i0 + m * 16 + lan;
      bq[m][kk] = *(const bf16x8*)&qr[(size_t)(i * NE + nn) * 1024 + hh * 64 + kk * 32 + lgr * 8];
    }
#pragma unroll
  for (int n = 0; n < 16; ++n) {
    bf16x8 bv[2];
#pragma unroll
    for (int kk = 0; kk < 2; ++kk) {
      const int jp = n * 16 + lan;
      bv[kk] = *(const bf16x8*)&rbf[(size_t)jp * 1024 + hh * 64 + kk * 32 + lgr * 8];
    }
#pragma unroll
    for (int m = 0; m < 2; ++m) {
      f32x4 a4 = (f32x4){0.f, 0.f, 0.f, 0.f};
#pragma unroll
      for (int kk = 0; kk < 2; ++kk)
        a4 = __builtin_amdgcn_mfma_f32_16x16x32_bf16(bq[m][kk], bv[kk], a4, 0, 0, 0);
#pragma unroll
      for (int e = 0; e < 4; ++e) {
        const int r = m * 16 + lgr * 4 + e;
        const int i = i0 + r;
        const int jp = n * 16 + lan;
        const int j = jp + i - 127;
        if (j >= 0 && j < 256) {
          const int swz = ((r >> 2) & 3) * 16;
          const int idx = r * 256 + (j ^ swz);
          S[idx] = f2bf(bf2f(S[idx]) + a4[e]);
        }
      }
    }
  }

  // ---- masked softmax, in place ----
  const int j0 = l * 4;
  for (int rr = 0; rr < 32; ++rr) {
    const int i = i0 + rr;
    const int epi = ep[i * NE + nn];
    const int swz = ((rr >> 2) & 3) * 16;
    s16x4 s4 = *(const s16x4*)&S[rr * 256 + (j0 ^ swz)];
    float sc[4];
#pragma unroll
    for (int q = 0; q < 4; ++q) {
      const int j = j0 + q;
      bool allow;
      if (j < M_) {
        allow = (epi == 0);
      } else {
        const int jp = j - M_;
        allow = (jp <= i) && (ep[jp * NE + nn] == epi);
      }
      sc[q] = allow ? bf2f((unsigned short)s4[q]) * 0.125f : -1e9f;
    }
    float mx = fmaxf(fmaxf(sc[0], sc[1]), fmaxf(sc[2], sc[3]));
#pragma unroll
    for (int o = 32; o; o >>= 1) mx = fmaxf(mx, __shfl_xor(mx, o));
    float p[4], sum = 0.f;
#pragma unroll
    for (int q = 0; q < 4; ++q) { p[q] = __expf(sc[q] - mx); sum += p[q]; }
#pragma unroll
    for (int o = 32; o; o >>= 1) sum += __shfl_xor(sum, o);
    const float inv = 1.f / sum;
    s16x4 o4;
#pragma unroll
    for (int q = 0; q < 4; ++q) o4[q] = (short)f2bf(p[q] * inv);
    *(s16x4*)&S[rr * 256 + (j0 ^ swz)] = o4;
  }

  // ---- PV ----
  const unsigned short* Vz = V + hh * DH_;
  f32x4 acc[2][4];
#pragma unroll
  for (int m = 0; m < 2; ++m)
#pragma unroll
    for (int n = 0; n < 4; ++n) acc[m][n] = (f32x4){0.f, 0.f, 0.f, 0.f};

  for (int ks = 0; ks < 8; ++ks) {
    const int kb = ks * 32 + lgr * 8;
    bf16x8 bv2[4];
#pragma unroll
    for (int n = 0; n < 4; ++n) {
      const int d = n * 16 + lan;
      bf16x8 tmp;
#pragma unroll
      for (int jj = 0; jj < 8; ++jj)
        tmp[jj] = (short)Vz[(size_t)((kb + jj) * NE + nn) * 1024 + d];
      bv2[n] = tmp;
    }
    bf16x8 pa[2];
#pragma unroll
    for (int m = 0; m < 2; ++m) {
      const int r = m * 16 + lan;
      const int swz = ((r >> 2) & 3) * 16;
      pa[m] = *(const bf16x8*)&S[r * 256 + (kb ^ swz)];
    }
#pragma unroll
    for (int m = 0; m < 2; ++m)
#pragma unroll
      for (int n = 0; n < 4; ++n)
        acc[m][n] = __builtin_amdgcn_mfma_f32_16x16x32_bf16(pa[m], bv2[n], acc[m][n], 0, 0, 0);
  }
#pragma unroll
  for (int m = 0; m < 2; ++m)
#pragma unroll
    for (int n = 0; n < 4; ++n)
#pragma unroll
      for (int e = 0; e < 4; ++e) {
        const int i = i0 + m * 16 + lgr * 4 + e;
        const int d = n * 16 + lan;
        O[(size_t)(i * NE + nn) * 1024 + hh * DH_ + d] = f2bf(acc[m][n][e]);
      }
}

// ---------------------------------------------------------------------------
// Batched weight transpose: 13 slices of 1024x1024 f32 -> bf16 transposed.
// ---------------------------------------------------------------------------
__global__ __launch_bounds__(256) void transpose13_kernel(
    const float* __restrict__ Wk, const float* __restrict__ Wv,
    const float* __restrict__ Wq, const float* __restrict__ Wr,
    const float* __restrict__ Wo, const float* __restrict__ W1,
    const float* __restrict__ W2,
    unsigned short* __restrict__ wtAll, unsigned short* __restrict__ wto,
    unsigned short* __restrict__ wt1, unsigned short* __restrict__ wt2)
{
  __shared__ float tile[32][33];
  const int zz = blockIdx.z;
  const float* W; unsigned short* WT; int Nd, Kd;
  if (zz < 5) {
    W = (zz == 0) ? Wk : (zz == 1) ? Wv : (zz == 2) ? Wq : (zz == 3) ? Wr : Wo;
    WT = (zz == 4) ? wto : (wtAll + (size_t)zz * 1024 * 1024);
    Nd = 1024; Kd = 1024;
  } else if (zz < 9) {
    const int c = zz - 5;
    W = W1 + (size_t)c * 1024;
    WT = wt1 + (size_t)c * 1024 * 1024;
    Nd = 4096; Kd = 1024;
  } else {
    const int c = zz - 9;
    W = W2 + (size_t)c * 1024 * 1024;
    WT = wt2 + (size_t)c * 1024;
    Nd = 1024; Kd = 4096;
  }
  const int tx = threadIdx.x & 31, ty = threadIdx.x >> 5;
  const int nIn = blockIdx.x * 32 + tx;
  const int kBase = blockIdx.y * 32;
#pragma unroll
  for (int r = 0; r < 32; r += 8)
    tile[ty + r][tx] = W[(size_t)(kBase + ty + r) * Nd + nIn];
  __syncthreads();
#pragma unroll
  for (int r = 0; r < 32; r += 8)
    WT[(size_t)(blockIdx.x * 32 + ty + r) * Kd + kBase + tx] = f2bf(tile[tx][ty + r]);
}

__global__ __launch_bounds__(256) void catmem_kernel(
    const float* __restrict__ mems_l, const float* __restrict__ masks,
    unsigned short* __restrict__ cat)
{
  const int idx = blockIdx.x * 256 + threadIdx.x;
  const int d = idx & 1023;
  const int r = idx >> 10;
  const int nn = r & 31, j = r >> 5;
  const float mk0 = masks[nn];
  cat[idx] = f2bf(mems_l[(size_t)(nn * M_ + j) * 1024 + d] * mk0);
}

// h = bf16(x + ctx) -> catUp (single residual copy)
__global__ __launch_bounds__(256) void hprep_kernel(
    const float* __restrict__ x, const float* __restrict__ ctx,
    unsigned short* __restrict__ catUp)
{
  const int idx = blockIdx.x * 256 + threadIdx.x;
  catUp[idx] = f2bf(x[idx] + ctx[idx]);
}

__global__ __launch_bounds__(256) void rpos_kernel(unsigned short* __restrict__ R)
{
  const int idx = blockIdx.x * 256 + threadIdx.x;
  const int d = idx & 1023, j = idx >> 10;
  const float pos = (float)(KLEN - 1 - j);
  const int f = d & 511;
  const float inv_freq = __expf(-((float)(2 * f) * (1.f / 1024.f)) * 9.210340371976184f);
  const float ang = pos * inv_freq;
  const float v = (d < 512) ? sinf(ang) : cosf(ang);
  R[idx] = f2bf(v);
}

__global__ void ep_kernel(const float* __restrict__ masks, int* __restrict__ ep)
{
  const int nn = threadIdx.x;
  if (nn < NE) {
    int c = 0;
    for (int i = 0; i < T_; ++i) {
      c += (masks[i * NE + nn] == 0.f) ? 1 : 0;
      ep[i * NE + nn] = c;
    }
  }
}

// y = LN(bf16_a + sum bf16_parts + bias) * g + b ; writes bf16 out (+f32 opt)
template <int NP, bool WRITEF>
__global__ __launch_bounds__(256) void ln_kernel(
    const unsigned short* __restrict__ a, const unsigned short* __restrict__ parts,
    size_t pstride, const float* __restrict__ bias,
    const float* __restrict__ g, const float* __restrict__ bb,
    unsigned short* __restrict__ outbf, float* __restrict__ outf)
{
  const int row = blockIdx.x;
  const int t = threadIdx.x, w = t >> 6, l = t & 63;
  const int c = t * 4;
  const size_t base = (size_t)row * 1024;
  s16x4 av = *(const s16x4*)&a[base + c];
  f32x4 v;
#pragma unroll
  for (int q = 0; q < 4; ++q) v[q] = bf2f((unsigned short)av[q]);
#pragma unroll
  for (int i = 0; i < NP; ++i) {
    s16x4 pv = *(const s16x4*)&parts[i * pstride + base + c];
#pragma unroll
    for (int q = 0; q < 4; ++q) v[q] += bf2f((unsigned short)pv[q]);
  }
  if (bias) v = v + *(const f32x4*)&bias[c];
  float s = v[0] + v[1] + v[2] + v[3];
#pragma unroll
  for (int o = 32; o; o >>= 1) s += __shfl_xor(s, o);
  __shared__ float red[8];
  if (l == 0) red[w] = s;
  __syncthreads();
  s = red[0] + red[1] + red[2] + red[3];
  const float mu = s * (1.f / 1024.f);
  f32x4 dv = v - mu;
  float s2 = dv[0]*dv[0] + dv[1]*dv[1] + dv[2]*dv[2] + dv[3]*dv[3];
#pragma unroll
  for (int o = 32; o; o >>= 1) s2 += __shfl_xor(s2, o);
  if (l == 0) red[4 + w] = s2;
  __syncthreads();
  s2 = red[4] + red[5] + red[6] + red[7];
  const float inv = rsqrtf(s2 * (1.f / 1024.f) + 1e-5f);
  f32x4 y;
#pragma unroll
  for (int q = 0; q < 4; ++q) y[q] = dv[q] * inv * g[c + q] + bb[c + q];
  s16x4 o4;
#pragma unroll
  for (int q = 0; q < 4; ++q) o4[q] = (short)f2bf(y[q]);
  *(s16x4*)&outbf[base + c] = o4;
  if (WRITEF) *(f32x4*)&outf[base + c] = y;
}

// ---------------------------------------------------------------------------
extern "C" void kernel_launch(void* const* d_in, const int* in_sizes, int n_in,
                              void* d_out, int out_size, void* d_ws, size_t ws_size,
                              hipStream_t stream)
{
  (void)in_sizes; (void)n_in; (void)out_size; (void)ws_size;
  const float* x    = (const float*)d_in[0];
  const float* ctx  = (const float*)d_in[1];
  const float* mems = (const float*)d_in[2];
  const float* masks= (const float*)d_in[3];
  const float* Wq   = (const float*)d_in[4];
  const float* Wk   = (const float*)d_in[5];
  const float* Wv   = (const float*)d_in[6];
  const float* Wr   = (const float*)d_in[7];
  const float* Wo   = (const float*)d_in[8];
  const float* W1   = (const float*)d_in[9];
  const float* b1   = (const float*)d_in[10];
  const float* W2   = (const float*)d_in[11];
  const float* b2   = (const float*)d_in[12];
  const float* ln1g = (const float*)d_in[13];
  const float* ln1b = (const float*)d_in[14];
  const float* ln2g = (const float*)d_in[15];
  const float* ln2b = (const float*)d_in[16];
  const float* rwb  = (const float*)d_in[17];
  const float* rrb  = (const float*)d_in[18];

  char* ws = (char*)d_ws;
  size_t off = 0;
  auto alloc = [&](size_t bytes) {
    char* p = ws + off;
    off += (bytes + 255) & ~(size_t)255;
    return p;
  };
  unsigned short* wtAll = (unsigned short*)alloc(4096u * 1024 * 2);  // [Wk|Wv|Wq|Wr]^T
  unsigned short* wto = (unsigned short*)alloc(1024u * 1024 * 2);
  unsigned short* wt1 = (unsigned short*)alloc(4096u * 1024 * 2);
  unsigned short* wt2 = (unsigned short*)alloc(4096u * 1024 * 2);
  unsigned short* cat = (unsigned short*)alloc((size_t)(KLEN * NE + 256) * 1024 * 2);
  unsigned short* rbf = (unsigned short*)alloc((size_t)KLEN * 1024 * 2);
  int*            epb = (int*)alloc((size_t)T_ * NE * 4);
  unsigned short* h1bf= (unsigned short*)alloc((size_t)TN * 1024 * 2);   // LN1 out
  unsigned short* qw  = (unsigned short*)alloc((size_t)TN * 1024 * 2);
  unsigned short* qr  = (unsigned short*)alloc((size_t)TN * 1024 * 2);
  unsigned short* kbf = (unsigned short*)alloc((size_t)KLEN * NE * 1024 * 2);
  unsigned short* vbf = (unsigned short*)alloc((size_t)KLEN * NE * 1024 * 2);
  unsigned short* ACb = (unsigned short*)alloc((size_t)NB * T_ * KLEN * 2); // alias: f1
  unsigned short* BDb = (unsigned short*)alloc((size_t)NB * T_ * KLEN * 2); // bf16 partials
  unsigned short* obf = (unsigned short*)alloc((size_t)TN * 1024 * 2);

  unsigned short* catUp = cat + (size_t)M_ * NE * 1024;     // residual stream (bf16)
  unsigned short* catR  = cat + (size_t)KLEN * NE * 1024;   // R rows (8192..8447)
  unsigned short* f1 = ACb;                 // W1 out
  unsigned short* part = BDb;               // 2 bf16 split-K partials (16 MB)

  rpos_kernel<<<KLEN * 1024 / 256, 256, 0, stream>>>(catR);
  ep_kernel<<<1, 64, 0, stream>>>(masks, epb);
  hprep_kernel<<<TN * 1024 / 256, 256, 0, stream>>>(x, ctx, catUp);

  for (int l = 0; l < L_; ++l) {
    const size_t wOff = (size_t)l * 1024 * 1024;
    const size_t wOffBig = (size_t)l * 1024 * 4096;
    transpose13_kernel<<<dim3(32, 32, 13), 256, 0, stream>>>(
        Wk + wOff, Wv + wOff, Wq + wOff, Wr + wOff, Wo + wOff,
        W1 + wOffBig, W2 + wOffBig, wtAll, wto, wt1, wt2);
    catmem_kernel<<<M_ * NE * 1024 / 256, 256, 0, stream>>>(
        mems + (size_t)l * NE * M_ * 1024, masks, cat);

    // fused k|v|q|r projection (1296 blocks, plain decode)
    gemm_proj<<<1296, 256, 0, stream>>>(cat, wtAll, kbf, vbf, qw, qr, rbf, rwb, rrb);

    // fully fused attention (scores + rel_shift + masked softmax + PV)
    attn_kernel<<<NB, 256, 0, stream>>>(qw, qr, kbf, rbf, epb, vbf, obf);

    // output projection, split-K=2 -> bf16 partials; reduce fused into LN1
    gemm_bt<1><<<512, 256, 0, stream>>>(obf, 1024, 0, 512,
                                        wto, 1024, 0, 512,
                                        part, 1024, TN * 1024, nullptr, 8, 2, 8, 32);
    // LN1: residual = catUp (bf16), out -> h1bf
    ln_kernel<2, false><<<TN, 256, 0, stream>>>(catUp, part, (size_t)TN * 1024, nullptr,
                                                ln1g + l * 1024, ln1b + l * 1024,
                                                h1bf, nullptr);

    // FFN: W1 on 256^2 core (256 blocks = 1 round/CU, bias+relu fused)
    gemm256_w1<<<dim3(16, 16), 512, 0, stream>>>(h1bf, wt1, f1, b1 + l * 4096);
    gemm_bt<1><<<512, 256, 0, stream>>>(f1, 4096, 0, 2048,
                                        wt2, 4096, 0, 2048,
                                        part, 1024, TN * 1024, nullptr, 32, 2, 8, 32);
    // LN2: residual = h1bf, out -> catUp (next layer); f32 d_out on last layer
    if (l == L_ - 1) {
      ln_kernel<2, true><<<TN, 256, 0, stream>>>(h1bf, part, (size_t)TN * 1024,
                                                 b2 + l * 1024, ln2g + l * 1024,
                                                 ln2b + l * 1024, catUp, (float*)d_out);
    } else {
      ln_kernel<2, false><<<TN, 256, 0, stream>>>(h1bf, part, (size_t)TN * 1024,
                                                  b2 + l * 1024, ln2g + l * 1024,
                                                  ln2b + l * 1024, catUp, nullptr);
    }
  }
}